// Round 1
// baseline (599.422 us; speedup 1.0000x reference)
//
#include <hip/hip_runtime.h>
#include <math.h>

static constexpr int NN = 100000;

#define CDIV(a,b) (((a)+(b)-1)/(b))

// ------------------------------------------------------------------
// degree histogram over dst
__global__ void k_hist(const int* __restrict__ dst, int* __restrict__ cnt, int E) {
    int e = blockIdx.x * 256 + threadIdx.x;
    if (e < E) atomicAdd(&cnt[dst[e]], 1);
}

// block sums of 1024 elements each
__global__ void k_reduceA(const int* __restrict__ cnt, int* __restrict__ bs, int n) {
    __shared__ int sm[256];
    int base = blockIdx.x * 1024;
    int s = 0;
    #pragma unroll
    for (int j = 0; j < 4; j++) {
        int idx = base + j * 256 + threadIdx.x;
        if (idx < n) s += cnt[idx];
    }
    sm[threadIdx.x] = s; __syncthreads();
    for (int off = 128; off > 0; off >>= 1) {
        if ((int)threadIdx.x < off) sm[threadIdx.x] += sm[threadIdx.x + off];
        __syncthreads();
    }
    if (threadIdx.x == 0) bs[blockIdx.x] = sm[0];
}

// exclusive scan of <=128 block sums (single block)
__global__ void k_scanB(int* bs, int nb) {
    __shared__ int sm[128];
    int v = ((int)threadIdx.x < nb) ? bs[threadIdx.x] : 0;
    sm[threadIdx.x] = v; __syncthreads();
    for (int off = 1; off < 128; off <<= 1) {
        int t = ((int)threadIdx.x >= off) ? sm[threadIdx.x - off] : 0;
        __syncthreads();
        sm[threadIdx.x] += t;
        __syncthreads();
    }
    if ((int)threadIdx.x < nb) bs[threadIdx.x] = sm[threadIdx.x] - v;
}

// full exclusive scan: local scan + block offset -> row_ptr
__global__ void k_scanC(const int* __restrict__ cnt, const int* __restrict__ bs,
                        int* __restrict__ row_ptr, int n, int E) {
    __shared__ int sm[256];
    int base = blockIdx.x * 1024 + threadIdx.x * 4;
    int a[4];
    #pragma unroll
    for (int j = 0; j < 4; j++) a[j] = (base + j < n) ? cnt[base + j] : 0;
    int tsum = a[0] + a[1] + a[2] + a[3];
    sm[threadIdx.x] = tsum; __syncthreads();
    for (int off = 1; off < 256; off <<= 1) {
        int t = ((int)threadIdx.x >= off) ? sm[threadIdx.x - off] : 0;
        __syncthreads();
        sm[threadIdx.x] += t;
        __syncthreads();
    }
    int ex = sm[threadIdx.x] - tsum + bs[blockIdx.x];
    int p = 0;
    #pragma unroll
    for (int j = 0; j < 4; j++) {
        if (base + j < n) row_ptr[base + j] = ex + p;
        p += a[j];
    }
    if (blockIdx.x == 0 && threadIdx.x == 0) row_ptr[n] = E;
}

__global__ void k_copy(const int* __restrict__ a, int* __restrict__ b, int n) {
    int i = blockIdx.x * 256 + threadIdx.x;
    if (i < n) b[i] = a[i];
}

// scatter edges into CSR buckets (dst-sorted), store src per slot
__global__ void k_scatter(const int* __restrict__ src, const int* __restrict__ dst,
                          int* __restrict__ fill, int* __restrict__ col, int E) {
    int e = blockIdx.x * 256 + threadIdx.x;
    if (e < E) {
        int d = dst[e];
        int pos = atomicAdd(&fill[d], 1);
        col[pos] = src[e];
    }
}

__global__ void k_dinv(const int* __restrict__ cnt, float* __restrict__ dinv, int n) {
    int i = blockIdx.x * 256 + threadIdx.x;
    if (i < n) dinv[i] = rsqrtf((float)(cnt[i] + 1));
}

// ------------------------------------------------------------------
// Tiled GEMM: OUT[nrows x NOUT] = X[nrows x K] @ W[K x NOUT]
// 64 rows per block, 256 threads, W-chunk + x-chunk in LDS.
template<int K, int NOUT>
__global__ __launch_bounds__(256) void k_gemm(const float* __restrict__ X,
                                              const float* __restrict__ W,
                                              float* __restrict__ OUT, int nrows) {
    constexpr int KC  = (K > 128) ? 128 : K;
    constexpr int CG  = NOUT / 4;   // float4 col groups
    constexpr int RPT = NOUT / 16;  // rows per thread
    __shared__ float xs[64][KC + 4];
    __shared__ float ws[KC][NOUT + 4];
    const int t = threadIdx.x;
    const int rbase = blockIdx.x * 64;
    const int c0 = (t % CG) * 4;
    const int rg = t / CG;
    float acc[RPT][4];
    #pragma unroll
    for (int r = 0; r < RPT; r++) acc[r][0] = acc[r][1] = acc[r][2] = acc[r][3] = 0.f;

    for (int kc = 0; kc < K; kc += KC) {
        for (int idx = t; idx < KC * NOUT / 4; idx += 256) {
            int wr = idx / (NOUT / 4), wc = (idx % (NOUT / 4)) * 4;
            *(float4*)&ws[wr][wc] = *(const float4*)&W[(size_t)(kc + wr) * NOUT + wc];
        }
        for (int idx = t; idx < 64 * KC / 4; idx += 256) {
            int xr = idx / (KC / 4), xc = (idx % (KC / 4)) * 4;
            float4 v = make_float4(0.f, 0.f, 0.f, 0.f);
            int gr = rbase + xr;
            if (gr < nrows) v = *(const float4*)&X[(size_t)gr * K + kc + xc];
            *(float4*)&xs[xr][xc] = v;
        }
        __syncthreads();
        #pragma unroll
        for (int k = 0; k < KC; k += 4) {
            float4 w0 = *(const float4*)&ws[k + 0][c0];
            float4 w1 = *(const float4*)&ws[k + 1][c0];
            float4 w2 = *(const float4*)&ws[k + 2][c0];
            float4 w3 = *(const float4*)&ws[k + 3][c0];
            #pragma unroll
            for (int r = 0; r < RPT; r++) {
                float4 xv = *(const float4*)&xs[rg * RPT + r][k];
                acc[r][0] += xv.x * w0.x + xv.y * w1.x + xv.z * w2.x + xv.w * w3.x;
                acc[r][1] += xv.x * w0.y + xv.y * w1.y + xv.z * w2.y + xv.w * w3.y;
                acc[r][2] += xv.x * w0.z + xv.y * w1.z + xv.z * w2.z + xv.w * w3.z;
                acc[r][3] += xv.x * w0.w + xv.y * w1.w + xv.z * w2.w + xv.w * w3.w;
            }
        }
        __syncthreads();
    }
    #pragma unroll
    for (int r = 0; r < RPT; r++) {
        int gr = rbase + rg * RPT + r;
        if (gr < nrows) {
            float4 o;
            o.x = acc[r][0]; o.y = acc[r][1]; o.z = acc[r][2]; o.w = acc[r][3];
            *(float4*)&OUT[(size_t)gr * NOUT + c0] = o;
        }
    }
}

// ------------------------------------------------------------------
// CSR gather-aggregate. F lanes own one node; MODE 0 = relu, 1 = log_softmax (F=64).
template<int F, int MODE>
__global__ __launch_bounds__(256) void k_agg(const float* __restrict__ H,
                                             const int* __restrict__ row_ptr,
                                             const int* __restrict__ col,
                                             const float* __restrict__ dinv,
                                             const float* __restrict__ bias,
                                             float* __restrict__ OUT, int n) {
    constexpr int NPB = 256 / F;
    int node = blockIdx.x * NPB + threadIdx.x / F;
    int c = threadIdx.x % F;
    if (node >= n) return;
    int s0 = row_ptr[node], s1 = row_ptr[node + 1];
    float acc0 = 0.f, acc1 = 0.f;
    int e = s0;
    for (; e + 1 < s1; e += 2) {
        int sA = col[e], sB = col[e + 1];
        acc0 += dinv[sA] * H[(size_t)sA * F + c];
        acc1 += dinv[sB] * H[(size_t)sB * F + c];
    }
    if (e < s1) {
        int sA = col[e];
        acc0 += dinv[sA] * H[(size_t)sA * F + c];
    }
    float di = dinv[node];
    float v = di * (acc0 + acc1 + di * H[(size_t)node * F + c]) + bias[c];
    if (MODE == 0) {
        OUT[(size_t)node * F + c] = fmaxf(v, 0.f);
    } else {
        float m = v;
        #pragma unroll
        for (int off = 32; off > 0; off >>= 1) m = fmaxf(m, __shfl_xor(m, off, 64));
        float ex = expf(v - m);
        float s = ex;
        #pragma unroll
        for (int off = 32; off > 0; off >>= 1) s += __shfl_xor(s, off, 64);
        OUT[(size_t)node * F + c] = v - m - logf(s);
    }
}

// ------------------------------------------------------------------
extern "C" void kernel_launch(void* const* d_in, const int* in_sizes, int n_in,
                              void* d_out, int out_size, void* d_ws, size_t ws_size,
                              hipStream_t stream) {
    const float* x  = (const float*)d_in[0];
    const int*   ei = (const int*)d_in[1];
    const float* W1 = (const float*)d_in[2];
    const float* b1 = (const float*)d_in[3];
    const float* W2 = (const float*)d_in[4];
    const float* b2 = (const float*)d_in[5];
    const float* W3 = (const float*)d_in[6];
    const float* b3 = (const float*)d_in[7];
    float* out = (float*)d_out;

    const int E = in_sizes[1] / 2;
    const int n = NN;
    const int* src = ei;
    const int* dst = ei + E;

    char* p = (char*)d_ws;
    auto alloc = [&](size_t bytes) -> void* {
        void* r = p;
        p += (bytes + 63) & ~(size_t)63;
        return r;
    };
    int*   cnt     = (int*)alloc((size_t)n * 4);
    int*   row_ptr = (int*)alloc((size_t)(n + 1) * 4);
    int*   bs      = (int*)alloc(128 * 4);
    int*   fill    = (int*)alloc((size_t)n * 4);
    int*   col     = (int*)alloc((size_t)E * 4);
    float* dinv    = (float*)alloc((size_t)n * 4);
    float* h       = (float*)alloc((size_t)n * 64 * 4);
    float* a       = (float*)alloc((size_t)n * 64 * 4);

    hipMemsetAsync(cnt, 0, (size_t)n * 4, stream);
    k_hist<<<CDIV(E, 256), 256, 0, stream>>>(dst, cnt, E);
    int nb = CDIV(n, 1024);
    k_reduceA<<<nb, 256, 0, stream>>>(cnt, bs, n);
    k_scanB<<<1, 128, 0, stream>>>(bs, nb);
    k_scanC<<<nb, 256, 0, stream>>>(cnt, bs, row_ptr, n, E);
    k_copy<<<CDIV(n, 256), 256, 0, stream>>>(row_ptr, fill, n);
    k_scatter<<<CDIV(E, 256), 256, 0, stream>>>(src, dst, fill, col, E);
    k_dinv<<<CDIV(n, 256), 256, 0, stream>>>(cnt, dinv, n);

    // layer 1: h = x @ W1 ; a = relu(agg(h) + b1)
    k_gemm<512, 32><<<CDIV(n, 64), 256, 0, stream>>>(x, W1, h, n);
    k_agg<32, 0><<<CDIV(n, 8), 256, 0, stream>>>(h, row_ptr, col, dinv, b1, a, n);
    // layer 2
    k_gemm<32, 32><<<CDIV(n, 64), 256, 0, stream>>>(a, W2, h, n);
    k_agg<32, 0><<<CDIV(n, 8), 256, 0, stream>>>(h, row_ptr, col, dinv, b2, a, n);
    // layer 3 + log_softmax
    k_gemm<32, 64><<<CDIV(n, 64), 256, 0, stream>>>(a, W3, h, n);
    k_agg<64, 1><<<CDIV(n, 4), 256, 0, stream>>>(h, row_ptr, col, dinv, b3, out, n);
}

// Round 2
// 582.810 us; speedup vs baseline: 1.0285x; 1.0285x over previous
//
#include <hip/hip_runtime.h>
#include <math.h>

static constexpr int NN = 100000;

#define CDIV(a,b) (((a)+(b)-1)/(b))

// ------------------------------------------------------------------
// degree histogram over dst
__global__ void k_hist(const int* __restrict__ dst, int* __restrict__ cnt, int E) {
    int e = blockIdx.x * 256 + threadIdx.x;
    if (e < E) atomicAdd(&cnt[dst[e]], 1);
}

// block sums of 1024 elements each
__global__ void k_reduceA(const int* __restrict__ cnt, int* __restrict__ bs, int n) {
    __shared__ int sm[256];
    int base = blockIdx.x * 1024;
    int s = 0;
    #pragma unroll
    for (int j = 0; j < 4; j++) {
        int idx = base + j * 256 + threadIdx.x;
        if (idx < n) s += cnt[idx];
    }
    sm[threadIdx.x] = s; __syncthreads();
    for (int off = 128; off > 0; off >>= 1) {
        if ((int)threadIdx.x < off) sm[threadIdx.x] += sm[threadIdx.x + off];
        __syncthreads();
    }
    if (threadIdx.x == 0) bs[blockIdx.x] = sm[0];
}

// exclusive scan of <=128 block sums (single block)
__global__ void k_scanB(int* bs, int nb) {
    __shared__ int sm[128];
    int v = ((int)threadIdx.x < nb) ? bs[threadIdx.x] : 0;
    sm[threadIdx.x] = v; __syncthreads();
    for (int off = 1; off < 128; off <<= 1) {
        int t = ((int)threadIdx.x >= off) ? sm[threadIdx.x - off] : 0;
        __syncthreads();
        sm[threadIdx.x] += t;
        __syncthreads();
    }
    if ((int)threadIdx.x < nb) bs[threadIdx.x] = sm[threadIdx.x] - v;
}

// full exclusive scan: local scan + block offset -> row_ptr
__global__ void k_scanC(const int* __restrict__ cnt, const int* __restrict__ bs,
                        int* __restrict__ row_ptr, int n, int E) {
    __shared__ int sm[256];
    int base = blockIdx.x * 1024 + threadIdx.x * 4;
    int a[4];
    #pragma unroll
    for (int j = 0; j < 4; j++) a[j] = (base + j < n) ? cnt[base + j] : 0;
    int tsum = a[0] + a[1] + a[2] + a[3];
    sm[threadIdx.x] = tsum; __syncthreads();
    for (int off = 1; off < 256; off <<= 1) {
        int t = ((int)threadIdx.x >= off) ? sm[threadIdx.x - off] : 0;
        __syncthreads();
        sm[threadIdx.x] += t;
        __syncthreads();
    }
    int ex = sm[threadIdx.x] - tsum + bs[blockIdx.x];
    int p = 0;
    #pragma unroll
    for (int j = 0; j < 4; j++) {
        if (base + j < n) row_ptr[base + j] = ex + p;
        p += a[j];
    }
    if (blockIdx.x == 0 && threadIdx.x == 0) row_ptr[n] = E;
}

__global__ void k_copy(const int* __restrict__ a, int* __restrict__ b, int n) {
    int i = blockIdx.x * 256 + threadIdx.x;
    if (i < n) b[i] = a[i];
}

// scatter edges into CSR buckets (dst-sorted), store src per slot
__global__ void k_scatter(const int* __restrict__ src, const int* __restrict__ dst,
                          int* __restrict__ fill, int* __restrict__ col, int E) {
    int e = blockIdx.x * 256 + threadIdx.x;
    if (e < E) {
        int d = dst[e];
        int pos = atomicAdd(&fill[d], 1);
        col[pos] = src[e];
    }
}

__global__ void k_dinv(const int* __restrict__ cnt, float* __restrict__ dinv, int n) {
    int i = blockIdx.x * 256 + threadIdx.x;
    if (i < n) dinv[i] = rsqrtf((float)(cnt[i] + 1));
}

// ------------------------------------------------------------------
// Register-blocked GEMM, no x-LDS, no barrier in k-loop.
// OUT[nrows x NOUT] = X[nrows x K] @ W[K x NOUT]
// Thread: MR=4 rows x 4 cols. Col-group lanes (CG of them) read the same
// x float4 (coalescer broadcast); W chunk lives in LDS (<=32 KB).
template<int K, int NOUT>
__global__ __launch_bounds__(256) void k_gemm(const float* __restrict__ X,
                                              const float* __restrict__ W,
                                              float* __restrict__ OUT, int nrows) {
    constexpr int KC    = (K > 256) ? 256 : K;   // K-chunk staged in LDS
    constexpr int CG    = NOUT / 4;              // col groups (float4-wide)
    constexpr int SLOTS = 256 / CG;              // row slots per block
    constexpr int MR    = 4;                     // rows per thread
    constexpr int RPB   = SLOTS * MR;            // rows per block
    __shared__ float ws[KC][NOUT];

    const int t    = threadIdx.x;
    const int c0   = (t % CG) * 4;
    const int slot = t / CG;
    const int row0 = blockIdx.x * RPB + slot * MR;

    float acc[MR][4];
    #pragma unroll
    for (int r = 0; r < MR; r++) acc[r][0] = acc[r][1] = acc[r][2] = acc[r][3] = 0.f;

    const float* xp[MR];
    #pragma unroll
    for (int r = 0; r < MR; r++) {
        int rr = row0 + r;
        if (rr > nrows - 1) rr = nrows - 1;      // clamp: safe load, store guarded
        xp[r] = X + (size_t)rr * K;
    }

    for (int kc = 0; kc < K; kc += KC) {
        if (kc) __syncthreads();                 // previous-chunk readers done
        for (int idx = t; idx < KC * NOUT / 4; idx += 256) {
            int wr = idx / (NOUT / 4), wc = (idx % (NOUT / 4)) * 4;
            *(float4*)&ws[wr][wc] = *(const float4*)&W[(size_t)(kc + wr) * NOUT + wc];
        }
        __syncthreads();
        #pragma unroll 4
        for (int k = 0; k < KC; k += 4) {
            float4 xv[MR];
            #pragma unroll
            for (int r = 0; r < MR; r++) xv[r] = *(const float4*)&xp[r][kc + k];
            float4 w0 = *(const float4*)&ws[k + 0][c0];
            float4 w1 = *(const float4*)&ws[k + 1][c0];
            float4 w2 = *(const float4*)&ws[k + 2][c0];
            float4 w3 = *(const float4*)&ws[k + 3][c0];
            #pragma unroll
            for (int r = 0; r < MR; r++) {
                acc[r][0] += xv[r].x * w0.x + xv[r].y * w1.x + xv[r].z * w2.x + xv[r].w * w3.x;
                acc[r][1] += xv[r].x * w0.y + xv[r].y * w1.y + xv[r].z * w2.y + xv[r].w * w3.y;
                acc[r][2] += xv[r].x * w0.z + xv[r].y * w1.z + xv[r].z * w2.z + xv[r].w * w3.z;
                acc[r][3] += xv[r].x * w0.w + xv[r].y * w1.w + xv[r].z * w2.w + xv[r].w * w3.w;
            }
        }
    }
    #pragma unroll
    for (int r = 0; r < MR; r++) {
        int rr = row0 + r;
        if (rr < nrows) {
            float4 o;
            o.x = acc[r][0]; o.y = acc[r][1]; o.z = acc[r][2]; o.w = acc[r][3];
            *(float4*)&OUT[(size_t)rr * NOUT + c0] = o;
        }
    }
}

// ------------------------------------------------------------------
// CSR gather-aggregate. F lanes own one node; MODE 0 = relu, 1 = log_softmax (F=64).
template<int F, int MODE>
__global__ __launch_bounds__(256) void k_agg(const float* __restrict__ H,
                                             const int* __restrict__ row_ptr,
                                             const int* __restrict__ col,
                                             const float* __restrict__ dinv,
                                             const float* __restrict__ bias,
                                             float* __restrict__ OUT, int n) {
    constexpr int NPB = 256 / F;
    int node = blockIdx.x * NPB + threadIdx.x / F;
    int c = threadIdx.x % F;
    if (node >= n) return;
    int s0 = row_ptr[node], s1 = row_ptr[node + 1];
    float acc0 = 0.f, acc1 = 0.f;
    int e = s0;
    for (; e + 1 < s1; e += 2) {
        int sA = col[e], sB = col[e + 1];
        acc0 += dinv[sA] * H[(size_t)sA * F + c];
        acc1 += dinv[sB] * H[(size_t)sB * F + c];
    }
    if (e < s1) {
        int sA = col[e];
        acc0 += dinv[sA] * H[(size_t)sA * F + c];
    }
    float di = dinv[node];
    float v = di * (acc0 + acc1 + di * H[(size_t)node * F + c]) + bias[c];
    if (MODE == 0) {
        OUT[(size_t)node * F + c] = fmaxf(v, 0.f);
    } else {
        float m = v;
        #pragma unroll
        for (int off = 32; off > 0; off >>= 1) m = fmaxf(m, __shfl_xor(m, off, 64));
        float ex = expf(v - m);
        float s = ex;
        #pragma unroll
        for (int off = 32; off > 0; off >>= 1) s += __shfl_xor(s, off, 64);
        OUT[(size_t)node * F + c] = v - m - logf(s);
    }
}

// ------------------------------------------------------------------
extern "C" void kernel_launch(void* const* d_in, const int* in_sizes, int n_in,
                              void* d_out, int out_size, void* d_ws, size_t ws_size,
                              hipStream_t stream) {
    const float* x  = (const float*)d_in[0];
    const int*   ei = (const int*)d_in[1];
    const float* W1 = (const float*)d_in[2];
    const float* b1 = (const float*)d_in[3];
    const float* W2 = (const float*)d_in[4];
    const float* b2 = (const float*)d_in[5];
    const float* W3 = (const float*)d_in[6];
    const float* b3 = (const float*)d_in[7];
    float* out = (float*)d_out;

    const int E = in_sizes[1] / 2;
    const int n = NN;
    const int* src = ei;
    const int* dst = ei + E;

    char* p = (char*)d_ws;
    auto alloc = [&](size_t bytes) -> void* {
        void* r = p;
        p += (bytes + 63) & ~(size_t)63;
        return r;
    };
    int*   cnt     = (int*)alloc((size_t)n * 4);
    int*   row_ptr = (int*)alloc((size_t)(n + 1) * 4);
    int*   bs      = (int*)alloc(128 * 4);
    int*   fill    = (int*)alloc((size_t)n * 4);
    int*   col     = (int*)alloc((size_t)E * 4);
    float* dinv    = (float*)alloc((size_t)n * 4);
    float* h       = (float*)alloc((size_t)n * 64 * 4);
    float* a       = (float*)alloc((size_t)n * 64 * 4);

    hipMemsetAsync(cnt, 0, (size_t)n * 4, stream);
    k_hist<<<CDIV(E, 256), 256, 0, stream>>>(dst, cnt, E);
    int nb = CDIV(n, 1024);
    k_reduceA<<<nb, 256, 0, stream>>>(cnt, bs, n);
    k_scanB<<<1, 128, 0, stream>>>(bs, nb);
    k_scanC<<<nb, 256, 0, stream>>>(cnt, bs, row_ptr, n, E);
    k_copy<<<CDIV(n, 256), 256, 0, stream>>>(row_ptr, fill, n);
    k_scatter<<<CDIV(E, 256), 256, 0, stream>>>(src, dst, fill, col, E);
    k_dinv<<<CDIV(n, 256), 256, 0, stream>>>(cnt, dinv, n);

    // layer 1: h = x @ W1 ; a = relu(agg(h) + b1)
    k_gemm<512, 32><<<CDIV(n, 128), 256, 0, stream>>>(x, W1, h, n);
    k_agg<32, 0><<<CDIV(n, 8), 256, 0, stream>>>(h, row_ptr, col, dinv, b1, a, n);
    // layer 2
    k_gemm<32, 32><<<CDIV(n, 128), 256, 0, stream>>>(a, W2, h, n);
    k_agg<32, 0><<<CDIV(n, 8), 256, 0, stream>>>(h, row_ptr, col, dinv, b2, a, n);
    // layer 3 + log_softmax
    k_gemm<32, 64><<<CDIV(n, 64), 256, 0, stream>>>(a, W3, h, n);
    k_agg<64, 1><<<CDIV(n, 4), 256, 0, stream>>>(h, row_ptr, col, dinv, b3, out, n);
}

// Round 3
// 531.642 us; speedup vs baseline: 1.1275x; 1.0962x over previous
//
#include <hip/hip_runtime.h>
#include <math.h>

static constexpr int NN = 100000;

#define CDIV(a,b) (((a)+(b)-1)/(b))

// ------------------------------------------------------------------
// degree histogram over dst
__global__ void k_hist(const int* __restrict__ dst, int* __restrict__ cnt, int E) {
    int e = blockIdx.x * 256 + threadIdx.x;
    if (e < E) atomicAdd(&cnt[dst[e]], 1);
}

// block sums of 1024 elements each
__global__ void k_reduceA(const int* __restrict__ cnt, int* __restrict__ bs, int n) {
    __shared__ int sm[256];
    int base = blockIdx.x * 1024;
    int s = 0;
    #pragma unroll
    for (int j = 0; j < 4; j++) {
        int idx = base + j * 256 + threadIdx.x;
        if (idx < n) s += cnt[idx];
    }
    sm[threadIdx.x] = s; __syncthreads();
    for (int off = 128; off > 0; off >>= 1) {
        if ((int)threadIdx.x < off) sm[threadIdx.x] += sm[threadIdx.x + off];
        __syncthreads();
    }
    if (threadIdx.x == 0) bs[blockIdx.x] = sm[0];
}

// exclusive scan of <=128 block sums (single block)
__global__ void k_scanB(int* bs, int nb) {
    __shared__ int sm[128];
    int v = ((int)threadIdx.x < nb) ? bs[threadIdx.x] : 0;
    sm[threadIdx.x] = v; __syncthreads();
    for (int off = 1; off < 128; off <<= 1) {
        int t = ((int)threadIdx.x >= off) ? sm[threadIdx.x - off] : 0;
        __syncthreads();
        sm[threadIdx.x] += t;
        __syncthreads();
    }
    if ((int)threadIdx.x < nb) bs[threadIdx.x] = sm[threadIdx.x] - v;
}

// full exclusive scan: local scan + block offset -> row_ptr
__global__ void k_scanC(const int* __restrict__ cnt, const int* __restrict__ bs,
                        int* __restrict__ row_ptr, int n, int E) {
    __shared__ int sm[256];
    int base = blockIdx.x * 1024 + threadIdx.x * 4;
    int a[4];
    #pragma unroll
    for (int j = 0; j < 4; j++) a[j] = (base + j < n) ? cnt[base + j] : 0;
    int tsum = a[0] + a[1] + a[2] + a[3];
    sm[threadIdx.x] = tsum; __syncthreads();
    for (int off = 1; off < 256; off <<= 1) {
        int t = ((int)threadIdx.x >= off) ? sm[threadIdx.x - off] : 0;
        __syncthreads();
        sm[threadIdx.x] += t;
        __syncthreads();
    }
    int ex = sm[threadIdx.x] - tsum + bs[blockIdx.x];
    int p = 0;
    #pragma unroll
    for (int j = 0; j < 4; j++) {
        if (base + j < n) row_ptr[base + j] = ex + p;
        p += a[j];
    }
    if (blockIdx.x == 0 && threadIdx.x == 0) row_ptr[n] = E;
}

__global__ void k_copy(const int* __restrict__ a, int* __restrict__ b, int n) {
    int i = blockIdx.x * 256 + threadIdx.x;
    if (i < n) b[i] = a[i];
}

// scatter edges into CSR buckets (dst-sorted), store src per slot
__global__ void k_scatter(const int* __restrict__ src, const int* __restrict__ dst,
                          int* __restrict__ fill, int* __restrict__ col, int E) {
    int e = blockIdx.x * 256 + threadIdx.x;
    if (e < E) {
        int d = dst[e];
        int pos = atomicAdd(&fill[d], 1);
        col[pos] = src[e];
    }
}

__global__ void k_dinv(const int* __restrict__ cnt, float* __restrict__ dinv, int n) {
    int i = blockIdx.x * 256 + threadIdx.x;
    if (i < n) dinv[i] = rsqrtf((float)(cnt[i] + 1));
}

// ------------------------------------------------------------------
// Register-blocked GEMM + dinv row-scale epilogue.
// OUT[r] = dinv[r] * (X[r] @ W)   (hs = dinv .* h)
// MR=2 rows/thread, W K-chunk in LDS, no barrier in k-loop.
template<int K, int NOUT>
__global__ __launch_bounds__(256) void k_gemm(const float* __restrict__ X,
                                              const float* __restrict__ W,
                                              const float* __restrict__ dinv,
                                              float* __restrict__ OUT, int nrows) {
    constexpr int KC    = (K > 256) ? 256 : K;   // K-chunk staged in LDS
    constexpr int CG    = NOUT / 4;              // col groups (float4-wide)
    constexpr int SLOTS = 256 / CG;              // row slots per block
    constexpr int MR    = 2;                     // rows per thread
    constexpr int RPB   = SLOTS * MR;            // rows per block
    __shared__ float ws[KC][NOUT];

    const int t    = threadIdx.x;
    const int c0   = (t % CG) * 4;
    const int slot = t / CG;
    const int row0 = blockIdx.x * RPB + slot * MR;

    float acc[MR][4];
    #pragma unroll
    for (int r = 0; r < MR; r++) acc[r][0] = acc[r][1] = acc[r][2] = acc[r][3] = 0.f;

    const float* xp[MR];
    #pragma unroll
    for (int r = 0; r < MR; r++) {
        int rr = row0 + r;
        if (rr > nrows - 1) rr = nrows - 1;      // clamp: safe load, store guarded
        xp[r] = X + (size_t)rr * K;
    }

    for (int kc = 0; kc < K; kc += KC) {
        if (kc) __syncthreads();                 // previous-chunk readers done
        for (int idx = t; idx < KC * NOUT / 4; idx += 256) {
            int wr = idx / (NOUT / 4), wc = (idx % (NOUT / 4)) * 4;
            *(float4*)&ws[wr][wc] = *(const float4*)&W[(size_t)(kc + wr) * NOUT + wc];
        }
        __syncthreads();
        #pragma unroll 8
        for (int k = 0; k < KC; k += 4) {
            float4 xv[MR];
            #pragma unroll
            for (int r = 0; r < MR; r++) xv[r] = *(const float4*)&xp[r][kc + k];
            float4 w0 = *(const float4*)&ws[k + 0][c0];
            float4 w1 = *(const float4*)&ws[k + 1][c0];
            float4 w2 = *(const float4*)&ws[k + 2][c0];
            float4 w3 = *(const float4*)&ws[k + 3][c0];
            #pragma unroll
            for (int r = 0; r < MR; r++) {
                acc[r][0] += xv[r].x * w0.x + xv[r].y * w1.x + xv[r].z * w2.x + xv[r].w * w3.x;
                acc[r][1] += xv[r].x * w0.y + xv[r].y * w1.y + xv[r].z * w2.y + xv[r].w * w3.y;
                acc[r][2] += xv[r].x * w0.z + xv[r].y * w1.z + xv[r].z * w2.z + xv[r].w * w3.z;
                acc[r][3] += xv[r].x * w0.w + xv[r].y * w1.w + xv[r].z * w2.w + xv[r].w * w3.w;
            }
        }
    }
    #pragma unroll
    for (int r = 0; r < MR; r++) {
        int rr = row0 + r;
        if (rr < nrows) {
            float d = dinv[rr];
            float4 o;
            o.x = acc[r][0] * d; o.y = acc[r][1] * d;
            o.z = acc[r][2] * d; o.w = acc[r][3] * d;
            *(float4*)&OUT[(size_t)rr * NOUT + c0] = o;
        }
    }
}

// ------------------------------------------------------------------
// CSR gather-aggregate over pre-scaled HS (= dinv .* H).
// out_i = dinv_i * (sum_{e: dst=i} HS[src_e] + HS[i]) + bias
// L = F/4 lanes per node, float4 gathers, 4-way unrolled chains.
// MODE 0 = relu, 1 = log_softmax over F channels.
template<int F, int MODE>
__global__ __launch_bounds__(256) void k_agg(const float* __restrict__ HS,
                                             const int* __restrict__ row_ptr,
                                             const int* __restrict__ col,
                                             const float* __restrict__ dinv,
                                             const float* __restrict__ bias,
                                             float* __restrict__ OUT, int n) {
    constexpr int L   = F / 4;       // lanes per node
    constexpr int NPB = 256 / L;     // nodes per block
    const int t    = threadIdx.x;
    const int node = blockIdx.x * NPB + t / L;
    const int c0   = (t % L) * 4;
    if (node >= n) return;
    const int s0 = row_ptr[node], s1 = row_ptr[node + 1];

    float4 a0 = {0,0,0,0}, a1 = {0,0,0,0}, a2 = {0,0,0,0}, a3 = {0,0,0,0};
    int e = s0;
    for (; e + 3 < s1; e += 4) {
        int sA = col[e], sB = col[e + 1], sC = col[e + 2], sD = col[e + 3];
        float4 vA = *(const float4*)&HS[(size_t)sA * F + c0];
        float4 vB = *(const float4*)&HS[(size_t)sB * F + c0];
        float4 vC = *(const float4*)&HS[(size_t)sC * F + c0];
        float4 vD = *(const float4*)&HS[(size_t)sD * F + c0];
        a0.x += vA.x; a0.y += vA.y; a0.z += vA.z; a0.w += vA.w;
        a1.x += vB.x; a1.y += vB.y; a1.z += vB.z; a1.w += vB.w;
        a2.x += vC.x; a2.y += vC.y; a2.z += vC.z; a2.w += vC.w;
        a3.x += vD.x; a3.y += vD.y; a3.z += vD.z; a3.w += vD.w;
    }
    for (; e < s1; e++) {
        int sA = col[e];
        float4 vA = *(const float4*)&HS[(size_t)sA * F + c0];
        a0.x += vA.x; a0.y += vA.y; a0.z += vA.z; a0.w += vA.w;
    }
    float4 self = *(const float4*)&HS[(size_t)node * F + c0];
    float4 acc;
    acc.x = a0.x + a1.x + a2.x + a3.x + self.x;
    acc.y = a0.y + a1.y + a2.y + a3.y + self.y;
    acc.z = a0.z + a1.z + a2.z + a3.z + self.z;
    acc.w = a0.w + a1.w + a2.w + a3.w + self.w;

    const float di = dinv[node];
    float4 b4 = *(const float4*)&bias[c0];
    float4 v;
    v.x = di * acc.x + b4.x;
    v.y = di * acc.y + b4.y;
    v.z = di * acc.z + b4.z;
    v.w = di * acc.w + b4.w;

    if (MODE == 0) {
        float4 o;
        o.x = fmaxf(v.x, 0.f); o.y = fmaxf(v.y, 0.f);
        o.z = fmaxf(v.z, 0.f); o.w = fmaxf(v.w, 0.f);
        *(float4*)&OUT[(size_t)node * F + c0] = o;
    } else {
        float m = fmaxf(fmaxf(v.x, v.y), fmaxf(v.z, v.w));
        #pragma unroll
        for (int off = 1; off < L; off <<= 1) m = fmaxf(m, __shfl_xor(m, off, 64));
        float s = expf(v.x - m) + expf(v.y - m) + expf(v.z - m) + expf(v.w - m);
        #pragma unroll
        for (int off = 1; off < L; off <<= 1) s += __shfl_xor(s, off, 64);
        float lse = m + logf(s);
        float4 o;
        o.x = v.x - lse; o.y = v.y - lse; o.z = v.z - lse; o.w = v.w - lse;
        *(float4*)&OUT[(size_t)node * F + c0] = o;
    }
}

// ------------------------------------------------------------------
extern "C" void kernel_launch(void* const* d_in, const int* in_sizes, int n_in,
                              void* d_out, int out_size, void* d_ws, size_t ws_size,
                              hipStream_t stream) {
    const float* x  = (const float*)d_in[0];
    const int*   ei = (const int*)d_in[1];
    const float* W1 = (const float*)d_in[2];
    const float* b1 = (const float*)d_in[3];
    const float* W2 = (const float*)d_in[4];
    const float* b2 = (const float*)d_in[5];
    const float* W3 = (const float*)d_in[6];
    const float* b3 = (const float*)d_in[7];
    float* out = (float*)d_out;

    const int E = in_sizes[1] / 2;
    const int n = NN;
    const int* src = ei;
    const int* dst = ei + E;

    char* p = (char*)d_ws;
    auto alloc = [&](size_t bytes) -> void* {
        void* r = p;
        p += (bytes + 63) & ~(size_t)63;
        return r;
    };
    int*   cnt     = (int*)alloc((size_t)n * 4);
    int*   row_ptr = (int*)alloc((size_t)(n + 1) * 4);
    int*   bs      = (int*)alloc(128 * 4);
    int*   fill    = (int*)alloc((size_t)n * 4);
    int*   col     = (int*)alloc((size_t)E * 4);
    float* dinv    = (float*)alloc((size_t)n * 4);
    float* h       = (float*)alloc((size_t)n * 64 * 4);
    float* a       = (float*)alloc((size_t)n * 64 * 4);

    hipMemsetAsync(cnt, 0, (size_t)n * 4, stream);
    k_hist<<<CDIV(E, 256), 256, 0, stream>>>(dst, cnt, E);
    int nb = CDIV(n, 1024);
    k_reduceA<<<nb, 256, 0, stream>>>(cnt, bs, n);
    k_scanB<<<1, 128, 0, stream>>>(bs, nb);
    k_scanC<<<nb, 256, 0, stream>>>(cnt, bs, row_ptr, n, E);
    k_copy<<<CDIV(n, 256), 256, 0, stream>>>(row_ptr, fill, n);
    k_scatter<<<CDIV(E, 256), 256, 0, stream>>>(src, dst, fill, col, E);
    k_dinv<<<CDIV(n, 256), 256, 0, stream>>>(cnt, dinv, n);

    // layer 1: hs = dinv.*(x @ W1) ; a = relu(dinv.*(agg(hs)+self) + b1)
    k_gemm<512, 32><<<CDIV(n, 64), 256, 0, stream>>>(x, W1, dinv, h, n);
    k_agg<32, 0><<<CDIV(n, 32), 256, 0, stream>>>(h, row_ptr, col, dinv, b1, a, n);
    // layer 2
    k_gemm<32, 32><<<CDIV(n, 64), 256, 0, stream>>>(a, W2, dinv, h, n);
    k_agg<32, 0><<<CDIV(n, 32), 256, 0, stream>>>(h, row_ptr, col, dinv, b2, a, n);
    // layer 3 + log_softmax
    k_gemm<32, 64><<<CDIV(n, 32), 256, 0, stream>>>(a, W3, dinv, h, n);
    k_agg<64, 1><<<CDIV(n, 16), 256, 0, stream>>>(h, row_ptr, col, dinv, b3, out, n);
}

// Round 4
// 492.454 us; speedup vs baseline: 1.2172x; 1.0796x over previous
//
#include <hip/hip_runtime.h>
#include <math.h>

static constexpr int NN = 100000;

#define CDIV(a,b) (((a)+(b)-1)/(b))

// ------------------------------------------------------------------
// degree histogram over dst
__global__ void k_hist(const int* __restrict__ dst, int* __restrict__ cnt, int E) {
    int e = blockIdx.x * 256 + threadIdx.x;
    if (e < E) atomicAdd(&cnt[dst[e]], 1);
}

// block sums of 1024 elements each
__global__ void k_reduceA(const int* __restrict__ cnt, int* __restrict__ bs, int n) {
    __shared__ int sm[256];
    int base = blockIdx.x * 1024;
    int s = 0;
    #pragma unroll
    for (int j = 0; j < 4; j++) {
        int idx = base + j * 256 + threadIdx.x;
        if (idx < n) s += cnt[idx];
    }
    sm[threadIdx.x] = s; __syncthreads();
    for (int off = 128; off > 0; off >>= 1) {
        if ((int)threadIdx.x < off) sm[threadIdx.x] += sm[threadIdx.x + off];
        __syncthreads();
    }
    if (threadIdx.x == 0) bs[blockIdx.x] = sm[0];
}

// exclusive scan of <=128 block sums (single block)
__global__ void k_scanB(int* bs, int nb) {
    __shared__ int sm[128];
    int v = ((int)threadIdx.x < nb) ? bs[threadIdx.x] : 0;
    sm[threadIdx.x] = v; __syncthreads();
    for (int off = 1; off < 128; off <<= 1) {
        int t = ((int)threadIdx.x >= off) ? sm[threadIdx.x - off] : 0;
        __syncthreads();
        sm[threadIdx.x] += t;
        __syncthreads();
    }
    if ((int)threadIdx.x < nb) bs[threadIdx.x] = sm[threadIdx.x] - v;
}

// full exclusive scan: local scan + block offset -> row_ptr
__global__ void k_scanC(const int* __restrict__ cnt, const int* __restrict__ bs,
                        int* __restrict__ row_ptr, int n, int E) {
    __shared__ int sm[256];
    int base = blockIdx.x * 1024 + threadIdx.x * 4;
    int a[4];
    #pragma unroll
    for (int j = 0; j < 4; j++) a[j] = (base + j < n) ? cnt[base + j] : 0;
    int tsum = a[0] + a[1] + a[2] + a[3];
    sm[threadIdx.x] = tsum; __syncthreads();
    for (int off = 1; off < 256; off <<= 1) {
        int t = ((int)threadIdx.x >= off) ? sm[threadIdx.x - off] : 0;
        __syncthreads();
        sm[threadIdx.x] += t;
        __syncthreads();
    }
    int ex = sm[threadIdx.x] - tsum + bs[blockIdx.x];
    int p = 0;
    #pragma unroll
    for (int j = 0; j < 4; j++) {
        if (base + j < n) row_ptr[base + j] = ex + p;
        p += a[j];
    }
    if (blockIdx.x == 0 && threadIdx.x == 0) row_ptr[n] = E;
}

__global__ void k_copy(const int* __restrict__ a, int* __restrict__ b, int n) {
    int i = blockIdx.x * 256 + threadIdx.x;
    if (i < n) b[i] = a[i];
}

// scatter edges into CSR buckets (dst-sorted), store src per slot
__global__ void k_scatter(const int* __restrict__ src, const int* __restrict__ dst,
                          int* __restrict__ fill, int* __restrict__ col, int E) {
    int e = blockIdx.x * 256 + threadIdx.x;
    if (e < E) {
        int d = dst[e];
        int pos = atomicAdd(&fill[d], 1);
        col[pos] = src[e];
    }
}

__global__ void k_dinv(const int* __restrict__ cnt, float* __restrict__ dinv, int n) {
    int i = blockIdx.x * 256 + threadIdx.x;
    if (i < n) dinv[i] = rsqrtf((float)(cnt[i] + 1));
}

// ------------------------------------------------------------------
// Layer-1 GEMM (K=512, NOUT=32): LDS-staged x, double-buffered, reg prefetch.
// OUT[r] = dinv[r] * (X[r] @ W)
// Block: 256 thr, 64 rows. Compute map: colgroup=t%8 (4 cols), slot=t/8, MR=2.
// Stage map: thread t stages x rows {t/8, 32+t/8}, k-quad t%8 (flat-coalesced),
// and one W quad. xs rows padded +4 floats: compute reads are 2-way (free),
// ws reads broadcast across slots, exact 32-bank spread across colgroups.
__global__ __launch_bounds__(256) void k_gemm1(const float* __restrict__ X,
                                               const float* __restrict__ W,
                                               const float* __restrict__ dinv,
                                               float* __restrict__ OUT, int nrows) {
    constexpr int K    = 512;
    constexpr int NOUT = 32;
    constexpr int KC   = 32;
    constexpr int RPB  = 64;
    constexpr int XST  = KC + 4;   // 36 floats: 144 B row stride, 16B aligned
    __shared__ float xs[2][RPB][XST];
    __shared__ float ws[2][KC][NOUT];

    const int t     = threadIdx.x;
    const int c0    = (t % 8) * 4;
    const int slot  = t / 8;
    const int grow0 = blockIdx.x * RPB;
    const int srow  = t / 8;       // staging x-row (and +32)
    const int skq   = t % 8;       // staging k-quad

    float acc[2][4] = {{0.f,0.f,0.f,0.f},{0.f,0.f,0.f,0.f}};

    auto clampRow = [&](int lrow) {
        int rr = grow0 + lrow;
        return (rr > nrows - 1) ? (nrows - 1) : rr;
    };
    const float* xrowA = X + (size_t)clampRow(srow) * K;
    const float* xrowB = X + (size_t)clampRow(32 + srow) * K;

    // stage chunk 0
    {
        float4 a = *(const float4*)&xrowA[skq * 4];
        float4 b = *(const float4*)&xrowB[skq * 4];
        float4 w = *(const float4*)&W[(size_t)srow * NOUT + skq * 4];
        *(float4*)&xs[0][srow][skq * 4]      = a;
        *(float4*)&xs[0][32 + srow][skq * 4] = b;
        *(float4*)&ws[0][srow][skq * 4]      = w;
    }
    __syncthreads();

    int buf = 0;
    const int r0 = slot * 2;
    for (int kc = 0; kc < K; kc += KC) {
        const bool more = (kc + KC < K);
        float4 pa, pb, pw;
        if (more) {  // prefetch next chunk into regs; latency hides under compute
            pa = *(const float4*)&xrowA[kc + KC + skq * 4];
            pb = *(const float4*)&xrowB[kc + KC + skq * 4];
            pw = *(const float4*)&W[(size_t)(kc + KC + srow) * NOUT + skq * 4];
        }
        #pragma unroll
        for (int k = 0; k < KC; k += 4) {
            float4 x0 = *(const float4*)&xs[buf][r0][k];
            float4 x1 = *(const float4*)&xs[buf][r0 + 1][k];
            float4 w0 = *(const float4*)&ws[buf][k + 0][c0];
            float4 w1 = *(const float4*)&ws[buf][k + 1][c0];
            float4 w2 = *(const float4*)&ws[buf][k + 2][c0];
            float4 w3 = *(const float4*)&ws[buf][k + 3][c0];
            acc[0][0] += x0.x*w0.x + x0.y*w1.x + x0.z*w2.x + x0.w*w3.x;
            acc[0][1] += x0.x*w0.y + x0.y*w1.y + x0.z*w2.y + x0.w*w3.y;
            acc[0][2] += x0.x*w0.z + x0.y*w1.z + x0.z*w2.z + x0.w*w3.z;
            acc[0][3] += x0.x*w0.w + x0.y*w1.w + x0.z*w2.w + x0.w*w3.w;
            acc[1][0] += x1.x*w0.x + x1.y*w1.x + x1.z*w2.x + x1.w*w3.x;
            acc[1][1] += x1.x*w0.y + x1.y*w1.y + x1.z*w2.y + x1.w*w3.y;
            acc[1][2] += x1.x*w0.z + x1.y*w1.z + x1.z*w2.z + x1.w*w3.z;
            acc[1][3] += x1.x*w0.w + x1.y*w1.w + x1.z*w2.w + x1.w*w3.w;
        }
        if (more) {
            // write buf^1: last read 2 barriers ago -> safe without extra barrier
            *(float4*)&xs[buf ^ 1][srow][skq * 4]      = pa;
            *(float4*)&xs[buf ^ 1][32 + srow][skq * 4] = pb;
            *(float4*)&ws[buf ^ 1][srow][skq * 4]      = pw;
            __syncthreads();
            buf ^= 1;
        }
    }
    #pragma unroll
    for (int r = 0; r < 2; r++) {
        int rr = grow0 + r0 + r;
        if (rr < nrows) {
            float d = dinv[rr];
            float4 o;
            o.x = acc[r][0] * d; o.y = acc[r][1] * d;
            o.z = acc[r][2] * d; o.w = acc[r][3] * d;
            *(float4*)&OUT[(size_t)rr * NOUT + c0] = o;
        }
    }
}

// ------------------------------------------------------------------
// Small-K register-blocked GEMM (layers 2/3): W chunk in LDS, x direct.
template<int K, int NOUT>
__global__ __launch_bounds__(256) void k_gemm(const float* __restrict__ X,
                                              const float* __restrict__ W,
                                              const float* __restrict__ dinv,
                                              float* __restrict__ OUT, int nrows) {
    constexpr int KC    = (K > 256) ? 256 : K;
    constexpr int CG    = NOUT / 4;
    constexpr int SLOTS = 256 / CG;
    constexpr int MR    = 2;
    constexpr int RPB   = SLOTS * MR;
    __shared__ float ws[KC][NOUT];

    const int t    = threadIdx.x;
    const int c0   = (t % CG) * 4;
    const int slot = t / CG;
    const int row0 = blockIdx.x * RPB + slot * MR;

    float acc[MR][4];
    #pragma unroll
    for (int r = 0; r < MR; r++) acc[r][0] = acc[r][1] = acc[r][2] = acc[r][3] = 0.f;

    const float* xp[MR];
    #pragma unroll
    for (int r = 0; r < MR; r++) {
        int rr = row0 + r;
        if (rr > nrows - 1) rr = nrows - 1;
        xp[r] = X + (size_t)rr * K;
    }

    for (int kc = 0; kc < K; kc += KC) {
        if (kc) __syncthreads();
        for (int idx = t; idx < KC * NOUT / 4; idx += 256) {
            int wr = idx / (NOUT / 4), wc = (idx % (NOUT / 4)) * 4;
            *(float4*)&ws[wr][wc] = *(const float4*)&W[(size_t)(kc + wr) * NOUT + wc];
        }
        __syncthreads();
        #pragma unroll 8
        for (int k = 0; k < KC; k += 4) {
            float4 xv[MR];
            #pragma unroll
            for (int r = 0; r < MR; r++) xv[r] = *(const float4*)&xp[r][kc + k];
            float4 w0 = *(const float4*)&ws[k + 0][c0];
            float4 w1 = *(const float4*)&ws[k + 1][c0];
            float4 w2 = *(const float4*)&ws[k + 2][c0];
            float4 w3 = *(const float4*)&ws[k + 3][c0];
            #pragma unroll
            for (int r = 0; r < MR; r++) {
                acc[r][0] += xv[r].x * w0.x + xv[r].y * w1.x + xv[r].z * w2.x + xv[r].w * w3.x;
                acc[r][1] += xv[r].x * w0.y + xv[r].y * w1.y + xv[r].z * w2.y + xv[r].w * w3.y;
                acc[r][2] += xv[r].x * w0.z + xv[r].y * w1.z + xv[r].z * w2.z + xv[r].w * w3.z;
                acc[r][3] += xv[r].x * w0.w + xv[r].y * w1.w + xv[r].z * w2.w + xv[r].w * w3.w;
            }
        }
    }
    #pragma unroll
    for (int r = 0; r < MR; r++) {
        int rr = row0 + r;
        if (rr < nrows) {
            float d = dinv[rr];
            float4 o;
            o.x = acc[r][0] * d; o.y = acc[r][1] * d;
            o.z = acc[r][2] * d; o.w = acc[r][3] * d;
            *(float4*)&OUT[(size_t)rr * NOUT + c0] = o;
        }
    }
}

// ------------------------------------------------------------------
// CSR gather-aggregate over pre-scaled HS (= dinv .* H).
// out_i = dinv_i * (sum_{e: dst=i} HS[src_e] + HS[i]) + bias
template<int F, int MODE>
__global__ __launch_bounds__(256) void k_agg(const float* __restrict__ HS,
                                             const int* __restrict__ row_ptr,
                                             const int* __restrict__ col,
                                             const float* __restrict__ dinv,
                                             const float* __restrict__ bias,
                                             float* __restrict__ OUT, int n) {
    constexpr int L   = F / 4;
    constexpr int NPB = 256 / L;
    const int t    = threadIdx.x;
    const int node = blockIdx.x * NPB + t / L;
    const int c0   = (t % L) * 4;
    if (node >= n) return;
    const int s0 = row_ptr[node], s1 = row_ptr[node + 1];

    float4 a0 = {0,0,0,0}, a1 = {0,0,0,0}, a2 = {0,0,0,0}, a3 = {0,0,0,0};
    int e = s0;
    for (; e + 3 < s1; e += 4) {
        int sA = col[e], sB = col[e + 1], sC = col[e + 2], sD = col[e + 3];
        float4 vA = *(const float4*)&HS[(size_t)sA * F + c0];
        float4 vB = *(const float4*)&HS[(size_t)sB * F + c0];
        float4 vC = *(const float4*)&HS[(size_t)sC * F + c0];
        float4 vD = *(const float4*)&HS[(size_t)sD * F + c0];
        a0.x += vA.x; a0.y += vA.y; a0.z += vA.z; a0.w += vA.w;
        a1.x += vB.x; a1.y += vB.y; a1.z += vB.z; a1.w += vB.w;
        a2.x += vC.x; a2.y += vC.y; a2.z += vC.z; a2.w += vC.w;
        a3.x += vD.x; a3.y += vD.y; a3.z += vD.z; a3.w += vD.w;
    }
    for (; e < s1; e++) {
        int sA = col[e];
        float4 vA = *(const float4*)&HS[(size_t)sA * F + c0];
        a0.x += vA.x; a0.y += vA.y; a0.z += vA.z; a0.w += vA.w;
    }
    float4 self = *(const float4*)&HS[(size_t)node * F + c0];
    float4 acc;
    acc.x = a0.x + a1.x + a2.x + a3.x + self.x;
    acc.y = a0.y + a1.y + a2.y + a3.y + self.y;
    acc.z = a0.z + a1.z + a2.z + a3.z + self.z;
    acc.w = a0.w + a1.w + a2.w + a3.w + self.w;

    const float di = dinv[node];
    float4 b4 = *(const float4*)&bias[c0];
    float4 v;
    v.x = di * acc.x + b4.x;
    v.y = di * acc.y + b4.y;
    v.z = di * acc.z + b4.z;
    v.w = di * acc.w + b4.w;

    if (MODE == 0) {
        float4 o;
        o.x = fmaxf(v.x, 0.f); o.y = fmaxf(v.y, 0.f);
        o.z = fmaxf(v.z, 0.f); o.w = fmaxf(v.w, 0.f);
        *(float4*)&OUT[(size_t)node * F + c0] = o;
    } else {
        float m = fmaxf(fmaxf(v.x, v.y), fmaxf(v.z, v.w));
        #pragma unroll
        for (int off = 1; off < L; off <<= 1) m = fmaxf(m, __shfl_xor(m, off, 64));
        float s = expf(v.x - m) + expf(v.y - m) + expf(v.z - m) + expf(v.w - m);
        #pragma unroll
        for (int off = 1; off < L; off <<= 1) s += __shfl_xor(s, off, 64);
        float lse = m + logf(s);
        float4 o;
        o.x = v.x - lse; o.y = v.y - lse; o.z = v.z - lse; o.w = v.w - lse;
        *(float4*)&OUT[(size_t)node * F + c0] = o;
    }
}

// ------------------------------------------------------------------
extern "C" void kernel_launch(void* const* d_in, const int* in_sizes, int n_in,
                              void* d_out, int out_size, void* d_ws, size_t ws_size,
                              hipStream_t stream) {
    const float* x  = (const float*)d_in[0];
    const int*   ei = (const int*)d_in[1];
    const float* W1 = (const float*)d_in[2];
    const float* b1 = (const float*)d_in[3];
    const float* W2 = (const float*)d_in[4];
    const float* b2 = (const float*)d_in[5];
    const float* W3 = (const float*)d_in[6];
    const float* b3 = (const float*)d_in[7];
    float* out = (float*)d_out;

    const int E = in_sizes[1] / 2;
    const int n = NN;
    const int* src = ei;
    const int* dst = ei + E;

    char* p = (char*)d_ws;
    auto alloc = [&](size_t bytes) -> void* {
        void* r = p;
        p += (bytes + 63) & ~(size_t)63;
        return r;
    };
    int*   cnt     = (int*)alloc((size_t)n * 4);
    int*   row_ptr = (int*)alloc((size_t)(n + 1) * 4);
    int*   bs      = (int*)alloc(128 * 4);
    int*   fill    = (int*)alloc((size_t)n * 4);
    int*   col     = (int*)alloc((size_t)E * 4);
    float* dinv    = (float*)alloc((size_t)n * 4);
    float* h       = (float*)alloc((size_t)n * 64 * 4);
    float* a       = (float*)alloc((size_t)n * 64 * 4);

    hipMemsetAsync(cnt, 0, (size_t)n * 4, stream);
    k_hist<<<CDIV(E, 256), 256, 0, stream>>>(dst, cnt, E);
    int nb = CDIV(n, 1024);
    k_reduceA<<<nb, 256, 0, stream>>>(cnt, bs, n);
    k_scanB<<<1, 128, 0, stream>>>(bs, nb);
    k_scanC<<<nb, 256, 0, stream>>>(cnt, bs, row_ptr, n, E);
    k_copy<<<CDIV(n, 256), 256, 0, stream>>>(row_ptr, fill, n);
    k_scatter<<<CDIV(E, 256), 256, 0, stream>>>(src, dst, fill, col, E);
    k_dinv<<<CDIV(n, 256), 256, 0, stream>>>(cnt, dinv, n);

    // layer 1: hs = dinv.*(x @ W1) ; a = relu(dinv.*(agg(hs)+self) + b1)
    k_gemm1<<<CDIV(n, 64), 256, 0, stream>>>(x, W1, dinv, h, n);
    k_agg<32, 0><<<CDIV(n, 32), 256, 0, stream>>>(h, row_ptr, col, dinv, b1, a, n);
    // layer 2
    k_gemm<32, 32><<<CDIV(n, 64), 256, 0, stream>>>(a, W2, dinv, h, n);
    k_agg<32, 0><<<CDIV(n, 32), 256, 0, stream>>>(h, row_ptr, col, dinv, b2, a, n);
    // layer 3 + log_softmax
    k_gemm<32, 64><<<CDIV(n, 32), 256, 0, stream>>>(a, W3, dinv, h, n);
    k_agg<64, 1><<<CDIV(n, 16), 256, 0, stream>>>(h, row_ptr, col, dinv, b3, out, n);
}

// Round 5
// 297.154 us; speedup vs baseline: 2.0172x; 1.6572x over previous
//
#include <hip/hip_runtime.h>
#include <math.h>

static constexpr int NN    = 100000;
static constexpr int NBUCK = (NN + 255) / 256;   // 391 buckets of 256 nodes

#define CDIV(a,b) (((a)+(b)-1)/(b))

// ------------------------------------------------------------------
// A1: per-bucket edge counts (LDS hist, one global atomic per block-bucket)
__global__ __launch_bounds__(256) void k_bcount(const int* __restrict__ dst,
                                                int* __restrict__ bcnt,
                                                int E, int chunk) {
    __shared__ int lc[NBUCK];
    for (int i = threadIdx.x; i < NBUCK; i += 256) lc[i] = 0;
    __syncthreads();
    int e0 = blockIdx.x * chunk;
    int e1 = e0 + chunk; if (e1 > E) e1 = E;
    for (int e = e0 + threadIdx.x; e < e1; e += 256)
        atomicAdd(&lc[dst[e] >> 8], 1);
    __syncthreads();
    for (int i = threadIdx.x; i < NBUCK; i += 256)
        if (lc[i]) atomicAdd(&bcnt[i], lc[i]);
}

// exclusive scan of bucket counts -> bbase (and bfill copy)
__global__ __launch_bounds__(512) void k_bscan(const int* __restrict__ bcnt,
                                               int* __restrict__ bbase,
                                               int* __restrict__ bfill, int E) {
    __shared__ int sm[512];
    int t = threadIdx.x;
    int v = (t < NBUCK) ? bcnt[t] : 0;
    sm[t] = v; __syncthreads();
    for (int off = 1; off < 512; off <<= 1) {
        int u = (t >= off) ? sm[t - off] : 0;
        __syncthreads();
        sm[t] += u;
        __syncthreads();
    }
    if (t < NBUCK) { int ex = sm[t] - v; bbase[t] = ex; bfill[t] = ex; }
    if (t == 0) bbase[NBUCK] = E;
}

// A2: partition edges into bucket-contiguous part[], packed (src<<8)|(dst&255)
__global__ __launch_bounds__(256) void k_bpart(const int* __restrict__ src,
                                               const int* __restrict__ dst,
                                               int* __restrict__ bfill,
                                               unsigned int* __restrict__ part,
                                               int E, int chunk) {
    __shared__ int lc[NBUCK];
    __shared__ int boff[NBUCK];
    for (int i = threadIdx.x; i < NBUCK; i += 256) lc[i] = 0;
    __syncthreads();
    int e0 = blockIdx.x * chunk;
    int e1 = e0 + chunk; if (e1 > E) e1 = E;
    for (int e = e0 + threadIdx.x; e < e1; e += 256)
        atomicAdd(&lc[dst[e] >> 8], 1);
    __syncthreads();
    for (int i = threadIdx.x; i < NBUCK; i += 256) {
        int c = lc[i];
        boff[i] = c ? atomicAdd(&bfill[i], c) : 0;
        lc[i] = 0;
    }
    __syncthreads();
    for (int e = e0 + threadIdx.x; e < e1; e += 256) {
        int d = dst[e];
        int b = d >> 8;
        int pos = boff[b] + atomicAdd(&lc[b], 1);
        part[pos] = ((unsigned)src[e] << 8) | (unsigned)(d & 255);
    }
}

// B: per-bucket CSR finalize: row_ptr, dinv, col (all writes bucket-local)
__global__ __launch_bounds__(256) void k_bbuild(const unsigned int* __restrict__ part,
                                                const int* __restrict__ bbase,
                                                int* __restrict__ row_ptr,
                                                float* __restrict__ dinv,
                                                int* __restrict__ col, int n, int E) {
    __shared__ int hist[256];
    __shared__ int excl[256];
    __shared__ int fill[256];
    const int b = blockIdx.x;
    const int t = threadIdx.x;
    const int e0 = bbase[b], e1 = bbase[b + 1];
    hist[t] = 0; fill[t] = 0;
    __syncthreads();
    for (int e = e0 + t; e < e1; e += 256)
        atomicAdd(&hist[part[e] & 255], 1);
    __syncthreads();
    int v = hist[t];
    excl[t] = v; __syncthreads();
    for (int off = 1; off < 256; off <<= 1) {
        int u = (t >= off) ? excl[t - off] : 0;
        __syncthreads();
        excl[t] += u;
        __syncthreads();
    }
    int ex = excl[t] - v;           // exclusive scan value
    int g = b * 256 + t;
    if (g < n) {
        row_ptr[g] = e0 + ex;
        dinv[g] = rsqrtf((float)(v + 1));
    }
    if (b == 0 && t == 0) row_ptr[n] = E;
    excl[t] = e0 + ex;              // repurpose as per-local-node col base
    __syncthreads();
    for (int e = e0 + t; e < e1; e += 256) {
        unsigned u = part[e];
        int ld = u & 255;
        int pos = excl[ld] + atomicAdd(&fill[ld], 1);
        col[pos] = (int)(u >> 8);
    }
}

// ------------------------------------------------------------------
// Layer-1 GEMM (K=512, NOUT=32): LDS-staged x, double-buffered, reg prefetch.
__global__ __launch_bounds__(256) void k_gemm1(const float* __restrict__ X,
                                               const float* __restrict__ W,
                                               const float* __restrict__ dinv,
                                               float* __restrict__ OUT, int nrows) {
    constexpr int K    = 512;
    constexpr int NOUT = 32;
    constexpr int KC   = 32;
    constexpr int RPB  = 64;
    constexpr int XST  = KC + 4;
    __shared__ float xs[2][RPB][XST];
    __shared__ float ws[2][KC][NOUT];

    const int t     = threadIdx.x;
    const int c0    = (t % 8) * 4;
    const int slot  = t / 8;
    const int grow0 = blockIdx.x * RPB;
    const int srow  = t / 8;
    const int skq   = t % 8;

    float acc[2][4] = {{0.f,0.f,0.f,0.f},{0.f,0.f,0.f,0.f}};

    auto clampRow = [&](int lrow) {
        int rr = grow0 + lrow;
        return (rr > nrows - 1) ? (nrows - 1) : rr;
    };
    const float* xrowA = X + (size_t)clampRow(srow) * K;
    const float* xrowB = X + (size_t)clampRow(32 + srow) * K;

    {
        float4 a = *(const float4*)&xrowA[skq * 4];
        float4 b = *(const float4*)&xrowB[skq * 4];
        float4 w = *(const float4*)&W[(size_t)srow * NOUT + skq * 4];
        *(float4*)&xs[0][srow][skq * 4]      = a;
        *(float4*)&xs[0][32 + srow][skq * 4] = b;
        *(float4*)&ws[0][srow][skq * 4]      = w;
    }
    __syncthreads();

    int buf = 0;
    const int r0 = slot * 2;
    for (int kc = 0; kc < K; kc += KC) {
        const bool more = (kc + KC < K);
        float4 pa, pb, pw;
        if (more) {
            pa = *(const float4*)&xrowA[kc + KC + skq * 4];
            pb = *(const float4*)&xrowB[kc + KC + skq * 4];
            pw = *(const float4*)&W[(size_t)(kc + KC + srow) * NOUT + skq * 4];
        }
        #pragma unroll
        for (int k = 0; k < KC; k += 4) {
            float4 x0 = *(const float4*)&xs[buf][r0][k];
            float4 x1 = *(const float4*)&xs[buf][r0 + 1][k];
            float4 w0 = *(const float4*)&ws[buf][k + 0][c0];
            float4 w1 = *(const float4*)&ws[buf][k + 1][c0];
            float4 w2 = *(const float4*)&ws[buf][k + 2][c0];
            float4 w3 = *(const float4*)&ws[buf][k + 3][c0];
            acc[0][0] += x0.x*w0.x + x0.y*w1.x + x0.z*w2.x + x0.w*w3.x;
            acc[0][1] += x0.x*w0.y + x0.y*w1.y + x0.z*w2.y + x0.w*w3.y;
            acc[0][2] += x0.x*w0.z + x0.y*w1.z + x0.z*w2.z + x0.w*w3.z;
            acc[0][3] += x0.x*w0.w + x0.y*w1.w + x0.z*w2.w + x0.w*w3.w;
            acc[1][0] += x1.x*w0.x + x1.y*w1.x + x1.z*w2.x + x1.w*w3.x;
            acc[1][1] += x1.x*w0.y + x1.y*w1.y + x1.z*w2.y + x1.w*w3.y;
            acc[1][2] += x1.x*w0.z + x1.y*w1.z + x1.z*w2.z + x1.w*w3.z;
            acc[1][3] += x1.x*w0.w + x1.y*w1.w + x1.z*w2.w + x1.w*w3.w;
        }
        if (more) {
            *(float4*)&xs[buf ^ 1][srow][skq * 4]      = pa;
            *(float4*)&xs[buf ^ 1][32 + srow][skq * 4] = pb;
            *(float4*)&ws[buf ^ 1][srow][skq * 4]      = pw;
            __syncthreads();
            buf ^= 1;
        }
    }
    #pragma unroll
    for (int r = 0; r < 2; r++) {
        int rr = grow0 + r0 + r;
        if (rr < nrows) {
            float d = dinv[rr];
            float4 o;
            o.x = acc[r][0] * d; o.y = acc[r][1] * d;
            o.z = acc[r][2] * d; o.w = acc[r][3] * d;
            *(float4*)&OUT[(size_t)rr * NOUT + c0] = o;
        }
    }
}

// ------------------------------------------------------------------
// Small-K register-blocked GEMM (layers 2/3): W chunk in LDS, x direct.
template<int K, int NOUT>
__global__ __launch_bounds__(256) void k_gemm(const float* __restrict__ X,
                                              const float* __restrict__ W,
                                              const float* __restrict__ dinv,
                                              float* __restrict__ OUT, int nrows) {
    constexpr int KC    = (K > 256) ? 256 : K;
    constexpr int CG    = NOUT / 4;
    constexpr int SLOTS = 256 / CG;
    constexpr int MR    = 2;
    constexpr int RPB   = SLOTS * MR;
    __shared__ float ws[KC][NOUT];

    const int t    = threadIdx.x;
    const int c0   = (t % CG) * 4;
    const int slot = t / CG;
    const int row0 = blockIdx.x * RPB + slot * MR;

    float acc[MR][4];
    #pragma unroll
    for (int r = 0; r < MR; r++) acc[r][0] = acc[r][1] = acc[r][2] = acc[r][3] = 0.f;

    const float* xp[MR];
    #pragma unroll
    for (int r = 0; r < MR; r++) {
        int rr = row0 + r;
        if (rr > nrows - 1) rr = nrows - 1;
        xp[r] = X + (size_t)rr * K;
    }

    for (int kc = 0; kc < K; kc += KC) {
        if (kc) __syncthreads();
        for (int idx = t; idx < KC * NOUT / 4; idx += 256) {
            int wr = idx / (NOUT / 4), wc = (idx % (NOUT / 4)) * 4;
            *(float4*)&ws[wr][wc] = *(const float4*)&W[(size_t)(kc + wr) * NOUT + wc];
        }
        __syncthreads();
        #pragma unroll 8
        for (int k = 0; k < KC; k += 4) {
            float4 xv[MR];
            #pragma unroll
            for (int r = 0; r < MR; r++) xv[r] = *(const float4*)&xp[r][kc + k];
            float4 w0 = *(const float4*)&ws[k + 0][c0];
            float4 w1 = *(const float4*)&ws[k + 1][c0];
            float4 w2 = *(const float4*)&ws[k + 2][c0];
            float4 w3 = *(const float4*)&ws[k + 3][c0];
            #pragma unroll
            for (int r = 0; r < MR; r++) {
                acc[r][0] += xv[r].x * w0.x + xv[r].y * w1.x + xv[r].z * w2.x + xv[r].w * w3.x;
                acc[r][1] += xv[r].x * w0.y + xv[r].y * w1.y + xv[r].z * w2.y + xv[r].w * w3.y;
                acc[r][2] += xv[r].x * w0.z + xv[r].y * w1.z + xv[r].z * w2.z + xv[r].w * w3.z;
                acc[r][3] += xv[r].x * w0.w + xv[r].y * w1.w + xv[r].z * w2.w + xv[r].w * w3.w;
            }
        }
    }
    #pragma unroll
    for (int r = 0; r < MR; r++) {
        int rr = row0 + r;
        if (rr < nrows) {
            float d = dinv[rr];
            float4 o;
            o.x = acc[r][0] * d; o.y = acc[r][1] * d;
            o.z = acc[r][2] * d; o.w = acc[r][3] * d;
            *(float4*)&OUT[(size_t)rr * NOUT + c0] = o;
        }
    }
}

// ------------------------------------------------------------------
// CSR gather-aggregate over pre-scaled HS (= dinv .* H).
template<int F, int MODE>
__global__ __launch_bounds__(256) void k_agg(const float* __restrict__ HS,
                                             const int* __restrict__ row_ptr,
                                             const int* __restrict__ col,
                                             const float* __restrict__ dinv,
                                             const float* __restrict__ bias,
                                             float* __restrict__ OUT, int n) {
    constexpr int L   = F / 4;
    constexpr int NPB = 256 / L;
    const int t    = threadIdx.x;
    const int node = blockIdx.x * NPB + t / L;
    const int c0   = (t % L) * 4;
    if (node >= n) return;
    const int s0 = row_ptr[node], s1 = row_ptr[node + 1];

    float4 a0 = {0,0,0,0}, a1 = {0,0,0,0}, a2 = {0,0,0,0}, a3 = {0,0,0,0};
    int e = s0;
    for (; e + 3 < s1; e += 4) {
        int sA = col[e], sB = col[e + 1], sC = col[e + 2], sD = col[e + 3];
        float4 vA = *(const float4*)&HS[(size_t)sA * F + c0];
        float4 vB = *(const float4*)&HS[(size_t)sB * F + c0];
        float4 vC = *(const float4*)&HS[(size_t)sC * F + c0];
        float4 vD = *(const float4*)&HS[(size_t)sD * F + c0];
        a0.x += vA.x; a0.y += vA.y; a0.z += vA.z; a0.w += vA.w;
        a1.x += vB.x; a1.y += vB.y; a1.z += vB.z; a1.w += vB.w;
        a2.x += vC.x; a2.y += vC.y; a2.z += vC.z; a2.w += vC.w;
        a3.x += vD.x; a3.y += vD.y; a3.z += vD.z; a3.w += vD.w;
    }
    for (; e < s1; e++) {
        int sA = col[e];
        float4 vA = *(const float4*)&HS[(size_t)sA * F + c0];
        a0.x += vA.x; a0.y += vA.y; a0.z += vA.z; a0.w += vA.w;
    }
    float4 self = *(const float4*)&HS[(size_t)node * F + c0];
    float4 acc;
    acc.x = a0.x + a1.x + a2.x + a3.x + self.x;
    acc.y = a0.y + a1.y + a2.y + a3.y + self.y;
    acc.z = a0.z + a1.z + a2.z + a3.z + self.z;
    acc.w = a0.w + a1.w + a2.w + a3.w + self.w;

    const float di = dinv[node];
    float4 b4 = *(const float4*)&bias[c0];
    float4 v;
    v.x = di * acc.x + b4.x;
    v.y = di * acc.y + b4.y;
    v.z = di * acc.z + b4.z;
    v.w = di * acc.w + b4.w;

    if (MODE == 0) {
        float4 o;
        o.x = fmaxf(v.x, 0.f); o.y = fmaxf(v.y, 0.f);
        o.z = fmaxf(v.z, 0.f); o.w = fmaxf(v.w, 0.f);
        *(float4*)&OUT[(size_t)node * F + c0] = o;
    } else {
        float m = fmaxf(fmaxf(v.x, v.y), fmaxf(v.z, v.w));
        #pragma unroll
        for (int off = 1; off < L; off <<= 1) m = fmaxf(m, __shfl_xor(m, off, 64));
        float s = expf(v.x - m) + expf(v.y - m) + expf(v.z - m) + expf(v.w - m);
        #pragma unroll
        for (int off = 1; off < L; off <<= 1) s += __shfl_xor(s, off, 64);
        float lse = m + logf(s);
        float4 o;
        o.x = v.x - lse; o.y = v.y - lse; o.z = v.z - lse; o.w = v.w - lse;
        *(float4*)&OUT[(size_t)node * F + c0] = o;
    }
}

// ------------------------------------------------------------------
extern "C" void kernel_launch(void* const* d_in, const int* in_sizes, int n_in,
                              void* d_out, int out_size, void* d_ws, size_t ws_size,
                              hipStream_t stream) {
    const float* x  = (const float*)d_in[0];
    const int*   ei = (const int*)d_in[1];
    const float* W1 = (const float*)d_in[2];
    const float* b1 = (const float*)d_in[3];
    const float* W2 = (const float*)d_in[4];
    const float* b2 = (const float*)d_in[5];
    const float* W3 = (const float*)d_in[6];
    const float* b3 = (const float*)d_in[7];
    float* out = (float*)d_out;

    const int E = in_sizes[1] / 2;
    const int n = NN;
    const int* src = ei;
    const int* dst = ei + E;

    char* p = (char*)d_ws;
    auto alloc = [&](size_t bytes) -> void* {
        void* r = p;
        p += (bytes + 63) & ~(size_t)63;
        return r;
    };
    int*      bcnt    = (int*)alloc((size_t)NBUCK * 4);
    int*      bbase   = (int*)alloc((size_t)(NBUCK + 1) * 4);
    int*      bfill   = (int*)alloc((size_t)NBUCK * 4);
    unsigned* part    = (unsigned*)alloc((size_t)E * 4);
    int*      row_ptr = (int*)alloc((size_t)(n + 1) * 4);
    int*      col     = (int*)alloc((size_t)E * 4);
    float*    dinv    = (float*)alloc((size_t)n * 4);
    float*    h       = (float*)alloc((size_t)n * 64 * 4);
    float*    a       = (float*)alloc((size_t)n * 32 * 4);

    const int NBLK_A = 256;
    const int chunk  = CDIV(E, NBLK_A);

    hipMemsetAsync(bcnt, 0, (size_t)NBUCK * 4, stream);
    k_bcount<<<NBLK_A, 256, 0, stream>>>(dst, bcnt, E, chunk);
    k_bscan<<<1, 512, 0, stream>>>(bcnt, bbase, bfill, E);
    k_bpart<<<NBLK_A, 256, 0, stream>>>(src, dst, bfill, part, E, chunk);
    k_bbuild<<<NBUCK, 256, 0, stream>>>(part, bbase, row_ptr, dinv, col, n, E);

    // layer 1: hs = dinv.*(x @ W1) ; a = relu(dinv.*(agg(hs)+self) + b1)
    k_gemm1<<<CDIV(n, 64), 256, 0, stream>>>(x, W1, dinv, h, n);
    k_agg<32, 0><<<CDIV(n, 32), 256, 0, stream>>>(h, row_ptr, col, dinv, b1, a, n);
    // layer 2
    k_gemm<32, 32><<<CDIV(n, 64), 256, 0, stream>>>(a, W2, dinv, h, n);
    k_agg<32, 0><<<CDIV(n, 32), 256, 0, stream>>>(h, row_ptr, col, dinv, b2, a, n);
    // layer 3 + log_softmax
    k_gemm<32, 64><<<CDIV(n, 32), 256, 0, stream>>>(a, W3, dinv, h, n);
    k_agg<64, 1><<<CDIV(n, 16), 256, 0, stream>>>(h, row_ptr, col, dinv, b3, out, n);
}

// Round 6
// 245.546 us; speedup vs baseline: 2.4412x; 1.2102x over previous
//
#include <hip/hip_runtime.h>
#include <math.h>

static constexpr int NN    = 100000;
static constexpr int NBUCK = (NN + 255) / 256;   // 391 buckets of 256 nodes

#define CDIV(a,b) (((a)+(b)-1)/(b))

// ------------------------------------------------------------------
__global__ __launch_bounds__(512) void k_zero(int* __restrict__ p, int n) {
    int i = blockIdx.x * 512 + threadIdx.x;
    if (i < n) p[i] = 0;
}

// A1: per-bucket edge counts (LDS hist, one global atomic per block-bucket)
__global__ __launch_bounds__(256) void k_bcount(const int* __restrict__ dst,
                                                int* __restrict__ bcnt,
                                                int E, int chunk) {
    __shared__ int lc[NBUCK];
    for (int i = threadIdx.x; i < NBUCK; i += 256) lc[i] = 0;
    __syncthreads();
    int e0 = blockIdx.x * chunk;
    int e1 = e0 + chunk; if (e1 > E) e1 = E;
    for (int e = e0 + threadIdx.x; e < e1; e += 256)
        atomicAdd(&lc[dst[e] >> 8], 1);
    __syncthreads();
    for (int i = threadIdx.x; i < NBUCK; i += 256)
        if (lc[i]) atomicAdd(&bcnt[i], lc[i]);
}

// exclusive scan of bucket counts -> bbase (and bfill copy)
__global__ __launch_bounds__(512) void k_bscan(const int* __restrict__ bcnt,
                                               int* __restrict__ bbase,
                                               int* __restrict__ bfill, int E) {
    __shared__ int sm[512];
    int t = threadIdx.x;
    int v = (t < NBUCK) ? bcnt[t] : 0;
    sm[t] = v; __syncthreads();
    for (int off = 1; off < 512; off <<= 1) {
        int u = (t >= off) ? sm[t - off] : 0;
        __syncthreads();
        sm[t] += u;
        __syncthreads();
    }
    if (t < NBUCK) { int ex = sm[t] - v; bbase[t] = ex; bfill[t] = ex; }
    if (t == 0) bbase[NBUCK] = E;
}

// A2: partition edges into bucket-contiguous part[], packed (src<<8)|(dst&255)
__global__ __launch_bounds__(256) void k_bpart(const int* __restrict__ src,
                                               const int* __restrict__ dst,
                                               int* __restrict__ bfill,
                                               unsigned int* __restrict__ part,
                                               int E, int chunk) {
    __shared__ int lc[NBUCK];
    __shared__ int boff[NBUCK];
    for (int i = threadIdx.x; i < NBUCK; i += 256) lc[i] = 0;
    __syncthreads();
    int e0 = blockIdx.x * chunk;
    int e1 = e0 + chunk; if (e1 > E) e1 = E;
    for (int e = e0 + threadIdx.x; e < e1; e += 256)
        atomicAdd(&lc[dst[e] >> 8], 1);
    __syncthreads();
    for (int i = threadIdx.x; i < NBUCK; i += 256) {
        int c = lc[i];
        boff[i] = c ? atomicAdd(&bfill[i], c) : 0;
        lc[i] = 0;
    }
    __syncthreads();
    for (int e = e0 + threadIdx.x; e < e1; e += 256) {
        int d = dst[e];
        int b = d >> 8;
        int pos = boff[b] + atomicAdd(&lc[b], 1);
        part[pos] = ((unsigned)src[e] << 8) | (unsigned)(d & 255);
    }
}

// B: per-bucket CSR finalize: row_ptr, dinv, col (all writes bucket-local)
__global__ __launch_bounds__(256) void k_bbuild(const unsigned int* __restrict__ part,
                                                const int* __restrict__ bbase,
                                                int* __restrict__ row_ptr,
                                                float* __restrict__ dinv,
                                                int* __restrict__ col, int n, int E) {
    __shared__ int hist[256];
    __shared__ int excl[256];
    __shared__ int fill[256];
    const int b = blockIdx.x;
    const int t = threadIdx.x;
    const int e0 = bbase[b], e1 = bbase[b + 1];
    hist[t] = 0; fill[t] = 0;
    __syncthreads();
    for (int e = e0 + t; e < e1; e += 256)
        atomicAdd(&hist[part[e] & 255], 1);
    __syncthreads();
    int v = hist[t];
    excl[t] = v; __syncthreads();
    for (int off = 1; off < 256; off <<= 1) {
        int u = (t >= off) ? excl[t - off] : 0;
        __syncthreads();
        excl[t] += u;
        __syncthreads();
    }
    int ex = excl[t] - v;
    int g = b * 256 + t;
    if (g < n) {
        row_ptr[g] = e0 + ex;
        dinv[g] = rsqrtf((float)(v + 1));
    }
    if (b == 0 && t == 0) row_ptr[n] = E;
    excl[t] = e0 + ex;
    __syncthreads();
    for (int e = e0 + t; e < e1; e += 256) {
        unsigned u = part[e];
        int ld = u & 255;
        int pos = excl[ld] + atomicAdd(&fill[ld], 1);
        col[pos] = (int)(u >> 8);
    }
}

// ------------------------------------------------------------------
// Layer-1 GEMM (K=512, NOUT=32): LDS-staged x, double-buffered, reg prefetch.
__global__ __launch_bounds__(256) void k_gemm1(const float* __restrict__ X,
                                               const float* __restrict__ W,
                                               const float* __restrict__ dinv,
                                               float* __restrict__ OUT, int nrows) {
    constexpr int K    = 512;
    constexpr int NOUT = 32;
    constexpr int KC   = 32;
    constexpr int RPB  = 64;
    constexpr int XST  = KC + 4;
    __shared__ float xs[2][RPB][XST];
    __shared__ float ws[2][KC][NOUT];

    const int t     = threadIdx.x;
    const int c0    = (t % 8) * 4;
    const int slot  = t / 8;
    const int grow0 = blockIdx.x * RPB;
    const int srow  = t / 8;
    const int skq   = t % 8;

    float acc[2][4] = {{0.f,0.f,0.f,0.f},{0.f,0.f,0.f,0.f}};

    auto clampRow = [&](int lrow) {
        int rr = grow0 + lrow;
        return (rr > nrows - 1) ? (nrows - 1) : rr;
    };
    const float* xrowA = X + (size_t)clampRow(srow) * K;
    const float* xrowB = X + (size_t)clampRow(32 + srow) * K;

    {
        float4 a = *(const float4*)&xrowA[skq * 4];
        float4 b = *(const float4*)&xrowB[skq * 4];
        float4 w = *(const float4*)&W[(size_t)srow * NOUT + skq * 4];
        *(float4*)&xs[0][srow][skq * 4]      = a;
        *(float4*)&xs[0][32 + srow][skq * 4] = b;
        *(float4*)&ws[0][srow][skq * 4]      = w;
    }
    __syncthreads();

    int buf = 0;
    const int r0 = slot * 2;
    for (int kc = 0; kc < K; kc += KC) {
        const bool more = (kc + KC < K);
        float4 pa, pb, pw;
        if (more) {
            pa = *(const float4*)&xrowA[kc + KC + skq * 4];
            pb = *(const float4*)&xrowB[kc + KC + skq * 4];
            pw = *(const float4*)&W[(size_t)(kc + KC + srow) * NOUT + skq * 4];
        }
        #pragma unroll
        for (int k = 0; k < KC; k += 4) {
            float4 x0 = *(const float4*)&xs[buf][r0][k];
            float4 x1 = *(const float4*)&xs[buf][r0 + 1][k];
            float4 w0 = *(const float4*)&ws[buf][k + 0][c0];
            float4 w1 = *(const float4*)&ws[buf][k + 1][c0];
            float4 w2 = *(const float4*)&ws[buf][k + 2][c0];
            float4 w3 = *(const float4*)&ws[buf][k + 3][c0];
            acc[0][0] += x0.x*w0.x + x0.y*w1.x + x0.z*w2.x + x0.w*w3.x;
            acc[0][1] += x0.x*w0.y + x0.y*w1.y + x0.z*w2.y + x0.w*w3.y;
            acc[0][2] += x0.x*w0.z + x0.y*w1.z + x0.z*w2.z + x0.w*w3.z;
            acc[0][3] += x0.x*w0.w + x0.y*w1.w + x0.z*w2.w + x0.w*w3.w;
            acc[1][0] += x1.x*w0.x + x1.y*w1.x + x1.z*w2.x + x1.w*w3.x;
            acc[1][1] += x1.x*w0.y + x1.y*w1.y + x1.z*w2.y + x1.w*w3.y;
            acc[1][2] += x1.x*w0.z + x1.y*w1.z + x1.z*w2.z + x1.w*w3.z;
            acc[1][3] += x1.x*w0.w + x1.y*w1.w + x1.z*w2.w + x1.w*w3.w;
        }
        if (more) {
            *(float4*)&xs[buf ^ 1][srow][skq * 4]      = pa;
            *(float4*)&xs[buf ^ 1][32 + srow][skq * 4] = pb;
            *(float4*)&ws[buf ^ 1][srow][skq * 4]      = pw;
            __syncthreads();
            buf ^= 1;
        }
    }
    #pragma unroll
    for (int r = 0; r < 2; r++) {
        int rr = grow0 + r0 + r;
        if (rr < nrows) {
            float d = dinv[rr];
            float4 o;
            o.x = acc[r][0] * d; o.y = acc[r][1] * d;
            o.z = acc[r][2] * d; o.w = acc[r][3] * d;
            *(float4*)&OUT[(size_t)rr * NOUT + c0] = o;
        }
    }
}

// ------------------------------------------------------------------
// Shared agg-gather body: 8 lanes per node, float4 channels c0, F=32.
#define AGG32_BODY(HS, acc)                                                   \
    float4 a0 = {0,0,0,0}, a1 = {0,0,0,0}, a2 = {0,0,0,0}, a3 = {0,0,0,0};    \
    {                                                                         \
        int e = s0;                                                           \
        for (; e + 3 < s1; e += 4) {                                          \
            int sA = col[e], sB = col[e+1], sC = col[e+2], sD = col[e+3];     \
            float4 vA = *(const float4*)&HS[(size_t)sA * 32 + c0];            \
            float4 vB = *(const float4*)&HS[(size_t)sB * 32 + c0];            \
            float4 vC = *(const float4*)&HS[(size_t)sC * 32 + c0];            \
            float4 vD = *(const float4*)&HS[(size_t)sD * 32 + c0];            \
            a0.x += vA.x; a0.y += vA.y; a0.z += vA.z; a0.w += vA.w;           \
            a1.x += vB.x; a1.y += vB.y; a1.z += vB.z; a1.w += vB.w;           \
            a2.x += vC.x; a2.y += vC.y; a2.z += vC.z; a2.w += vC.w;           \
            a3.x += vD.x; a3.y += vD.y; a3.z += vD.z; a3.w += vD.w;           \
        }                                                                     \
        for (; e < s1; e++) {                                                 \
            int sA = col[e];                                                  \
            float4 vA = *(const float4*)&HS[(size_t)sA * 32 + c0];            \
            a0.x += vA.x; a0.y += vA.y; a0.z += vA.z; a0.w += vA.w;           \
        }                                                                     \
    }                                                                         \
    float4 self4 = *(const float4*)&HS[(size_t)node * 32 + c0];               \
    float4 acc;                                                               \
    acc.x = a0.x + a1.x + a2.x + a3.x + self4.x;                              \
    acc.y = a0.y + a1.y + a2.y + a3.y + self4.y;                              \
    acc.z = a0.z + a1.z + a2.z + a3.z + self4.z;                              \
    acc.w = a0.w + a1.w + a2.w + a3.w + self4.w;

// fuse: a = relu(dinv*(agg hs1) + b1); OUT = dinv * (a @ W2)  [32 -> 32]
__global__ __launch_bounds__(256) void k_fuse32(const float* __restrict__ HS,
                                                const int* __restrict__ row_ptr,
                                                const int* __restrict__ col,
                                                const float* __restrict__ dinv,
                                                const float* __restrict__ bin,
                                                const float* __restrict__ W,
                                                float* __restrict__ OUT, int n) {
    __shared__ float ws[32][32];
    {
        int i = threadIdx.x;                 // 256 float4s = 32x32
        int r = i / 8, c = (i % 8) * 4;
        *(float4*)&ws[r][c] = *(const float4*)&W[r * 32 + c];
    }
    __syncthreads();
    const int t    = threadIdx.x;
    const int node = blockIdx.x * 32 + t / 8;
    const int c0   = (t % 8) * 4;
    if (node >= n) return;
    const int s0 = row_ptr[node], s1 = row_ptr[node + 1];
    AGG32_BODY(HS, acc)
    const float di = dinv[node];
    float4 b4 = *(const float4*)&bin[c0];
    float4 a;
    a.x = fmaxf(di * acc.x + b4.x, 0.f);
    a.y = fmaxf(di * acc.y + b4.y, 0.f);
    a.z = fmaxf(di * acc.z + b4.z, 0.f);
    a.w = fmaxf(di * acc.w + b4.w, 0.f);
    // o[c0..c0+3] = di * sum_k a_full[k] * ws[k][c0..]
    float4 o = {0,0,0,0};
    const int gb = (t & 63) & ~7;
    #pragma unroll
    for (int s = 0; s < 8; s++) {
        float4 as;
        as.x = __shfl(a.x, gb + s, 64);
        as.y = __shfl(a.y, gb + s, 64);
        as.z = __shfl(a.z, gb + s, 64);
        as.w = __shfl(a.w, gb + s, 64);
        const int k0 = s * 4;
        float4 w0 = *(const float4*)&ws[k0 + 0][c0];
        float4 w1 = *(const float4*)&ws[k0 + 1][c0];
        float4 w2 = *(const float4*)&ws[k0 + 2][c0];
        float4 w3 = *(const float4*)&ws[k0 + 3][c0];
        o.x += as.x*w0.x + as.y*w1.x + as.z*w2.x + as.w*w3.x;
        o.y += as.x*w0.y + as.y*w1.y + as.z*w2.y + as.w*w3.y;
        o.z += as.x*w0.z + as.y*w1.z + as.z*w2.z + as.w*w3.z;
        o.w += as.x*w0.w + as.y*w1.w + as.z*w2.w + as.w*w3.w;
    }
    o.x *= di; o.y *= di; o.z *= di; o.w *= di;
    *(float4*)&OUT[(size_t)node * 32 + c0] = o;
}

// agg + bias + relu + dinv scale (prepares ys2 = dinv.*a2 for commuted layer 3)
__global__ __launch_bounds__(256) void k_aggscale(const float* __restrict__ HS,
                                                  const int* __restrict__ row_ptr,
                                                  const int* __restrict__ col,
                                                  const float* __restrict__ dinv,
                                                  const float* __restrict__ bin,
                                                  float* __restrict__ OUT, int n) {
    const int t    = threadIdx.x;
    const int node = blockIdx.x * 32 + t / 8;
    const int c0   = (t % 8) * 4;
    if (node >= n) return;
    const int s0 = row_ptr[node], s1 = row_ptr[node + 1];
    AGG32_BODY(HS, acc)
    const float di = dinv[node];
    float4 b4 = *(const float4*)&bin[c0];
    float4 o;
    o.x = di * fmaxf(di * acc.x + b4.x, 0.f);
    o.y = di * fmaxf(di * acc.y + b4.y, 0.f);
    o.z = di * fmaxf(di * acc.z + b4.z, 0.f);
    o.w = di * fmaxf(di * acc.w + b4.w, 0.f);
    *(float4*)&OUT[(size_t)node * 32 + c0] = o;
}

// final: g = dinv*(agg ys2); h3 = g @ W3 + b3 [32->64]; out = log_softmax(h3)
__global__ __launch_bounds__(256) void k_fuseC(const float* __restrict__ YS,
                                               const int* __restrict__ row_ptr,
                                               const int* __restrict__ col,
                                               const float* __restrict__ dinv,
                                               const float* __restrict__ b3,
                                               const float* __restrict__ W,
                                               float* __restrict__ OUT, int n) {
    __shared__ float ws[32][64];
    {
        int i = threadIdx.x;                  // 512 float4s = 32x64 -> 2 each
        int r0w = i / 16, cw = (i % 16) * 4;
        *(float4*)&ws[r0w][cw]      = *(const float4*)&W[r0w * 64 + cw];
        *(float4*)&ws[r0w + 16][cw] = *(const float4*)&W[(r0w + 16) * 64 + cw];
    }
    __syncthreads();
    const int t    = threadIdx.x;
    const int node = blockIdx.x * 32 + t / 8;
    const int c0   = (t % 8) * 4;
    if (node >= n) return;
    const int s0 = row_ptr[node], s1 = row_ptr[node + 1];
    AGG32_BODY(YS, acc)
    const float di = dinv[node];
    float4 g;
    g.x = di * acc.x; g.y = di * acc.y; g.z = di * acc.z; g.w = di * acc.w;
    // h3 at columns [c0..c0+3] and [32+c0..32+c0+3]
    float4 oL = {0,0,0,0}, oH = {0,0,0,0};
    const int gb = (t & 63) & ~7;
    #pragma unroll
    for (int s = 0; s < 8; s++) {
        float4 gs;
        gs.x = __shfl(g.x, gb + s, 64);
        gs.y = __shfl(g.y, gb + s, 64);
        gs.z = __shfl(g.z, gb + s, 64);
        gs.w = __shfl(g.w, gb + s, 64);
        const int k0 = s * 4;
        #pragma unroll
        for (int q = 0; q < 4; q++) {
            float gv = (q == 0) ? gs.x : (q == 1) ? gs.y : (q == 2) ? gs.z : gs.w;
            float4 wL = *(const float4*)&ws[k0 + q][c0];
            float4 wH = *(const float4*)&ws[k0 + q][32 + c0];
            oL.x += gv * wL.x; oL.y += gv * wL.y; oL.z += gv * wL.z; oL.w += gv * wL.w;
            oH.x += gv * wH.x; oH.y += gv * wH.y; oH.z += gv * wH.z; oH.w += gv * wH.w;
        }
    }
    float4 bL = *(const float4*)&b3[c0];
    float4 bH = *(const float4*)&b3[32 + c0];
    oL.x += bL.x; oL.y += bL.y; oL.z += bL.z; oL.w += bL.w;
    oH.x += bH.x; oH.y += bH.y; oH.z += bH.z; oH.w += bH.w;
    // log-softmax over 64 channels (8 per lane, 8 lanes per node)
    float m = fmaxf(fmaxf(fmaxf(oL.x, oL.y), fmaxf(oL.z, oL.w)),
                    fmaxf(fmaxf(oH.x, oH.y), fmaxf(oH.z, oH.w)));
    #pragma unroll
    for (int off = 1; off < 8; off <<= 1) m = fmaxf(m, __shfl_xor(m, off, 64));
    float sum = expf(oL.x - m) + expf(oL.y - m) + expf(oL.z - m) + expf(oL.w - m)
              + expf(oH.x - m) + expf(oH.y - m) + expf(oH.z - m) + expf(oH.w - m);
    #pragma unroll
    for (int off = 1; off < 8; off <<= 1) sum += __shfl_xor(sum, off, 64);
    float lse = m + logf(sum);
    float4 rL, rH;
    rL.x = oL.x - lse; rL.y = oL.y - lse; rL.z = oL.z - lse; rL.w = oL.w - lse;
    rH.x = oH.x - lse; rH.y = oH.y - lse; rH.z = oH.z - lse; rH.w = oH.w - lse;
    *(float4*)&OUT[(size_t)node * 64 + c0]      = rL;
    *(float4*)&OUT[(size_t)node * 64 + 32 + c0] = rH;
}

// ------------------------------------------------------------------
extern "C" void kernel_launch(void* const* d_in, const int* in_sizes, int n_in,
                              void* d_out, int out_size, void* d_ws, size_t ws_size,
                              hipStream_t stream) {
    const float* x  = (const float*)d_in[0];
    const int*   ei = (const int*)d_in[1];
    const float* W1 = (const float*)d_in[2];
    const float* b1 = (const float*)d_in[3];
    const float* W2 = (const float*)d_in[4];
    const float* b2 = (const float*)d_in[5];
    const float* W3 = (const float*)d_in[6];
    const float* b3 = (const float*)d_in[7];
    float* out = (float*)d_out;

    const int E = in_sizes[1] / 2;
    const int n = NN;
    const int* src = ei;
    const int* dst = ei + E;

    char* p = (char*)d_ws;
    auto alloc = [&](size_t bytes) -> void* {
        void* r = p;
        p += (bytes + 63) & ~(size_t)63;
        return r;
    };
    int*      bcnt    = (int*)alloc((size_t)NBUCK * 4);
    int*      bbase   = (int*)alloc((size_t)(NBUCK + 1) * 4);
    int*      bfill   = (int*)alloc((size_t)NBUCK * 4);
    unsigned* part    = (unsigned*)alloc((size_t)E * 4);
    int*      row_ptr = (int*)alloc((size_t)(n + 1) * 4);
    int*      col     = (int*)alloc((size_t)E * 4);
    float*    dinv    = (float*)alloc((size_t)n * 4);
    float*    hs1     = (float*)alloc((size_t)n * 32 * 4);  // also reused as ys2
    float*    hs2     = (float*)alloc((size_t)n * 32 * 4);

    const int NBLK_A = 256;
    const int chunk  = CDIV(E, NBLK_A);

    k_zero<<<1, 512, 0, stream>>>(bcnt, NBUCK);
    k_bcount<<<NBLK_A, 256, 0, stream>>>(dst, bcnt, E, chunk);
    k_bscan<<<1, 512, 0, stream>>>(bcnt, bbase, bfill, E);
    k_bpart<<<NBLK_A, 256, 0, stream>>>(src, dst, bfill, part, E, chunk);
    k_bbuild<<<NBUCK, 256, 0, stream>>>(part, bbase, row_ptr, dinv, col, n, E);

    // L1 GEMM: hs1 = dinv.*(x @ W1)
    k_gemm1<<<CDIV(n, 64), 256, 0, stream>>>(x, W1, dinv, hs1, n);
    // L1 agg + relu + L2 GEMM: hs2 = dinv.*(relu(dinv*agg(hs1)+b1) @ W2)
    k_fuse32<<<CDIV(n, 32), 256, 0, stream>>>(hs1, row_ptr, col, dinv, b1, W2, hs2, n);
    // L2 agg + relu + scale: ys2 = dinv.*relu(dinv*agg(hs2)+b2)   (reuse hs1)
    k_aggscale<<<CDIV(n, 32), 256, 0, stream>>>(hs2, row_ptr, col, dinv, b2, hs1, n);
    // L3 (commuted): out = lsm( (dinv*agg(ys2)) @ W3 + b3 )
    k_fuseC<<<CDIV(n, 32), 256, 0, stream>>>(hs1, row_ptr, col, dinv, b3, W3, out, n);
}

// Round 7
// 223.177 us; speedup vs baseline: 2.6859x; 1.1002x over previous
//
#include <hip/hip_runtime.h>
#include <math.h>

static constexpr int NN    = 100000;
static constexpr int NBUCK = (NN + 255) / 256;   // 391 buckets of 256 nodes

#define CDIV(a,b) (((a)+(b)-1)/(b))

// bf16 helpers (round-to-nearest-even store, shift load)
__device__ __forceinline__ float bf2f(unsigned short u) {
    return __uint_as_float(((unsigned)u) << 16);
}
__device__ __forceinline__ unsigned short f2bf(float f) {
    unsigned u = __float_as_uint(f);
    u += 0x7fffu + ((u >> 16) & 1u);
    return (unsigned short)(u >> 16);
}

// ------------------------------------------------------------------
__global__ __launch_bounds__(512) void k_zero(int* __restrict__ p, int n) {
    int i = blockIdx.x * 512 + threadIdx.x;
    if (i < n) p[i] = 0;
}

// A1: per-bucket edge counts (LDS hist, one global atomic per block-bucket)
__global__ __launch_bounds__(256) void k_bcount(const int* __restrict__ dst,
                                                int* __restrict__ bcnt,
                                                int E, int chunk) {
    __shared__ int lc[NBUCK];
    for (int i = threadIdx.x; i < NBUCK; i += 256) lc[i] = 0;
    __syncthreads();
    int e0 = blockIdx.x * chunk;
    int e1 = e0 + chunk; if (e1 > E) e1 = E;
    for (int e = e0 + threadIdx.x; e < e1; e += 256)
        atomicAdd(&lc[dst[e] >> 8], 1);
    __syncthreads();
    for (int i = threadIdx.x; i < NBUCK; i += 256)
        if (lc[i]) atomicAdd(&bcnt[i], lc[i]);
}

// exclusive scan of bucket counts -> bbase (and bfill copy)
__global__ __launch_bounds__(512) void k_bscan(const int* __restrict__ bcnt,
                                               int* __restrict__ bbase,
                                               int* __restrict__ bfill, int E) {
    __shared__ int sm[512];
    int t = threadIdx.x;
    int v = (t < NBUCK) ? bcnt[t] : 0;
    sm[t] = v; __syncthreads();
    for (int off = 1; off < 512; off <<= 1) {
        int u = (t >= off) ? sm[t - off] : 0;
        __syncthreads();
        sm[t] += u;
        __syncthreads();
    }
    if (t < NBUCK) { int ex = sm[t] - v; bbase[t] = ex; bfill[t] = ex; }
    if (t == 0) bbase[NBUCK] = E;
}

// A2: partition edges into bucket-contiguous part[], packed (src<<8)|(dst&255)
__global__ __launch_bounds__(256) void k_bpart(const int* __restrict__ src,
                                               const int* __restrict__ dst,
                                               int* __restrict__ bfill,
                                               unsigned int* __restrict__ part,
                                               int E, int chunk) {
    __shared__ int lc[NBUCK];
    __shared__ int boff[NBUCK];
    for (int i = threadIdx.x; i < NBUCK; i += 256) lc[i] = 0;
    __syncthreads();
    int e0 = blockIdx.x * chunk;
    int e1 = e0 + chunk; if (e1 > E) e1 = E;
    for (int e = e0 + threadIdx.x; e < e1; e += 256)
        atomicAdd(&lc[dst[e] >> 8], 1);
    __syncthreads();
    for (int i = threadIdx.x; i < NBUCK; i += 256) {
        int c = lc[i];
        boff[i] = c ? atomicAdd(&bfill[i], c) : 0;
        lc[i] = 0;
    }
    __syncthreads();
    for (int e = e0 + threadIdx.x; e < e1; e += 256) {
        int d = dst[e];
        int b = d >> 8;
        int pos = boff[b] + atomicAdd(&lc[b], 1);
        part[pos] = ((unsigned)src[e] << 8) | (unsigned)(d & 255);
    }
}

// B: per-bucket CSR finalize: row_ptr, dinv, col (all writes bucket-local)
__global__ __launch_bounds__(256) void k_bbuild(const unsigned int* __restrict__ part,
                                                const int* __restrict__ bbase,
                                                int* __restrict__ row_ptr,
                                                float* __restrict__ dinv,
                                                int* __restrict__ col, int n, int E) {
    __shared__ int hist[256];
    __shared__ int excl[256];
    __shared__ int fill[256];
    const int b = blockIdx.x;
    const int t = threadIdx.x;
    const int e0 = bbase[b], e1 = bbase[b + 1];
    hist[t] = 0; fill[t] = 0;
    __syncthreads();
    for (int e = e0 + t; e < e1; e += 256)
        atomicAdd(&hist[part[e] & 255], 1);
    __syncthreads();
    int v = hist[t];
    excl[t] = v; __syncthreads();
    for (int off = 1; off < 256; off <<= 1) {
        int u = (t >= off) ? excl[t - off] : 0;
        __syncthreads();
        excl[t] += u;
        __syncthreads();
    }
    int ex = excl[t] - v;
    int g = b * 256 + t;
    if (g < n) {
        row_ptr[g] = e0 + ex;
        dinv[g] = rsqrtf((float)(v + 1));
    }
    if (b == 0 && t == 0) row_ptr[n] = E;
    excl[t] = e0 + ex;
    __syncthreads();
    for (int e = e0 + t; e < e1; e += 256) {
        unsigned u = part[e];
        int ld = u & 255;
        int pos = excl[ld] + atomicAdd(&fill[ld], 1);
        col[pos] = (int)(u >> 8);
    }
}

// ------------------------------------------------------------------
// Layer-1 GEMM (K=512, NOUT=32): LDS-staged x, double-buffered, reg prefetch.
// OUT (bf16) = dinv[r] * (X[r] @ W)
__global__ __launch_bounds__(256) void k_gemm1(const float* __restrict__ X,
                                               const float* __restrict__ W,
                                               const float* __restrict__ dinv,
                                               unsigned short* __restrict__ OUT,
                                               int nrows) {
    constexpr int K    = 512;
    constexpr int NOUT = 32;
    constexpr int KC   = 32;
    constexpr int RPB  = 64;
    constexpr int XST  = KC + 4;
    __shared__ float xs[2][RPB][XST];
    __shared__ float ws[2][KC][NOUT];

    const int t     = threadIdx.x;
    const int c0    = (t % 8) * 4;
    const int slot  = t / 8;
    const int grow0 = blockIdx.x * RPB;
    const int srow  = t / 8;
    const int skq   = t % 8;

    float acc[2][4] = {{0.f,0.f,0.f,0.f},{0.f,0.f,0.f,0.f}};

    auto clampRow = [&](int lrow) {
        int rr = grow0 + lrow;
        return (rr > nrows - 1) ? (nrows - 1) : rr;
    };
    const float* xrowA = X + (size_t)clampRow(srow) * K;
    const float* xrowB = X + (size_t)clampRow(32 + srow) * K;

    {
        float4 a = *(const float4*)&xrowA[skq * 4];
        float4 b = *(const float4*)&xrowB[skq * 4];
        float4 w = *(const float4*)&W[(size_t)srow * NOUT + skq * 4];
        *(float4*)&xs[0][srow][skq * 4]      = a;
        *(float4*)&xs[0][32 + srow][skq * 4] = b;
        *(float4*)&ws[0][srow][skq * 4]      = w;
    }
    __syncthreads();

    int buf = 0;
    const int r0 = slot * 2;
    for (int kc = 0; kc < K; kc += KC) {
        const bool more = (kc + KC < K);
        float4 pa, pb, pw;
        if (more) {
            pa = *(const float4*)&xrowA[kc + KC + skq * 4];
            pb = *(const float4*)&xrowB[kc + KC + skq * 4];
            pw = *(const float4*)&W[(size_t)(kc + KC + srow) * NOUT + skq * 4];
        }
        #pragma unroll
        for (int k = 0; k < KC; k += 4) {
            float4 x0 = *(const float4*)&xs[buf][r0][k];
            float4 x1 = *(const float4*)&xs[buf][r0 + 1][k];
            float4 w0 = *(const float4*)&ws[buf][k + 0][c0];
            float4 w1 = *(const float4*)&ws[buf][k + 1][c0];
            float4 w2 = *(const float4*)&ws[buf][k + 2][c0];
            float4 w3 = *(const float4*)&ws[buf][k + 3][c0];
            acc[0][0] += x0.x*w0.x + x0.y*w1.x + x0.z*w2.x + x0.w*w3.x;
            acc[0][1] += x0.x*w0.y + x0.y*w1.y + x0.z*w2.y + x0.w*w3.y;
            acc[0][2] += x0.x*w0.z + x0.y*w1.z + x0.z*w2.z + x0.w*w3.z;
            acc[0][3] += x0.x*w0.w + x0.y*w1.w + x0.z*w2.w + x0.w*w3.w;
            acc[1][0] += x1.x*w0.x + x1.y*w1.x + x1.z*w2.x + x1.w*w3.x;
            acc[1][1] += x1.x*w0.y + x1.y*w1.y + x1.z*w2.y + x1.w*w3.y;
            acc[1][2] += x1.x*w0.z + x1.y*w1.z + x1.z*w2.z + x1.w*w3.z;
            acc[1][3] += x1.x*w0.w + x1.y*w1.w + x1.z*w2.w + x1.w*w3.w;
        }
        if (more) {
            *(float4*)&xs[buf ^ 1][srow][skq * 4]      = pa;
            *(float4*)&xs[buf ^ 1][32 + srow][skq * 4] = pb;
            *(float4*)&ws[buf ^ 1][srow][skq * 4]      = pw;
            __syncthreads();
            buf ^= 1;
        }
    }
    #pragma unroll
    for (int r = 0; r < 2; r++) {
        int rr = grow0 + r0 + r;
        if (rr < nrows) {
            float d = dinv[rr];
            ushort4 o;
            o.x = f2bf(acc[r][0] * d); o.y = f2bf(acc[r][1] * d);
            o.z = f2bf(acc[r][2] * d); o.w = f2bf(acc[r][3] * d);
            *(ushort4*)&OUT[(size_t)rr * NOUT + c0] = o;
        }
    }
}

// ------------------------------------------------------------------
// bf16 gather-aggregate core: 8 lanes/node, lane owns channels [c0..c0+3].
// Returns sum over incoming edges + self of HS rows (f32 accumulate).
__device__ __forceinline__ float4 agg_gather_bf16(const unsigned short* __restrict__ HS,
                                                  const int* __restrict__ col,
                                                  int s0, int s1, int node, int c0) {
    float4 a0 = {0,0,0,0}, a1 = {0,0,0,0}, a2 = {0,0,0,0}, a3 = {0,0,0,0};
    int e = s0;
    for (; e + 3 < s1; e += 4) {
        int sA = col[e], sB = col[e + 1], sC = col[e + 2], sD = col[e + 3];
        ushort4 uA = *(const ushort4*)&HS[(size_t)sA * 32 + c0];
        ushort4 uB = *(const ushort4*)&HS[(size_t)sB * 32 + c0];
        ushort4 uC = *(const ushort4*)&HS[(size_t)sC * 32 + c0];
        ushort4 uD = *(const ushort4*)&HS[(size_t)sD * 32 + c0];
        a0.x += bf2f(uA.x); a0.y += bf2f(uA.y); a0.z += bf2f(uA.z); a0.w += bf2f(uA.w);
        a1.x += bf2f(uB.x); a1.y += bf2f(uB.y); a1.z += bf2f(uB.z); a1.w += bf2f(uB.w);
        a2.x += bf2f(uC.x); a2.y += bf2f(uC.y); a2.z += bf2f(uC.z); a2.w += bf2f(uC.w);
        a3.x += bf2f(uD.x); a3.y += bf2f(uD.y); a3.z += bf2f(uD.z); a3.w += bf2f(uD.w);
    }
    for (; e < s1; e++) {
        int sA = col[e];
        ushort4 uA = *(const ushort4*)&HS[(size_t)sA * 32 + c0];
        a0.x += bf2f(uA.x); a0.y += bf2f(uA.y); a0.z += bf2f(uA.z); a0.w += bf2f(uA.w);
    }
    ushort4 uS = *(const ushort4*)&HS[(size_t)node * 32 + c0];
    float4 acc;
    acc.x = a0.x + a1.x + a2.x + a3.x + bf2f(uS.x);
    acc.y = a0.y + a1.y + a2.y + a3.y + bf2f(uS.y);
    acc.z = a0.z + a1.z + a2.z + a3.z + bf2f(uS.z);
    acc.w = a0.w + a1.w + a2.w + a3.w + bf2f(uS.w);
    return acc;
}

// fuse: a = relu(dinv*(agg hs1) + b1); OUT(bf16) = dinv * (a @ W2)  [32 -> 32]
__global__ __launch_bounds__(256) void k_fuse32(const unsigned short* __restrict__ HS,
                                                const int* __restrict__ row_ptr,
                                                const int* __restrict__ col,
                                                const float* __restrict__ dinv,
                                                const float* __restrict__ bin,
                                                const float* __restrict__ W,
                                                unsigned short* __restrict__ OUT, int n) {
    __shared__ float ws[32][32];
    {
        int i = threadIdx.x;                 // 256 float4s = 32x32
        int r = i / 8, c = (i % 8) * 4;
        *(float4*)&ws[r][c] = *(const float4*)&W[r * 32 + c];
    }
    __syncthreads();
    const int t    = threadIdx.x;
    const int node = blockIdx.x * 32 + t / 8;
    const int c0   = (t % 8) * 4;
    if (node >= n) return;
    const int s0 = row_ptr[node], s1 = row_ptr[node + 1];
    float4 acc = agg_gather_bf16(HS, col, s0, s1, node, c0);
    const float di = dinv[node];
    float4 b4 = *(const float4*)&bin[c0];
    float4 a;
    a.x = fmaxf(di * acc.x + b4.x, 0.f);
    a.y = fmaxf(di * acc.y + b4.y, 0.f);
    a.z = fmaxf(di * acc.z + b4.z, 0.f);
    a.w = fmaxf(di * acc.w + b4.w, 0.f);
    float4 o = {0,0,0,0};
    const int gb = (t & 63) & ~7;
    #pragma unroll
    for (int s = 0; s < 8; s++) {
        float4 as;
        as.x = __shfl(a.x, gb + s, 64);
        as.y = __shfl(a.y, gb + s, 64);
        as.z = __shfl(a.z, gb + s, 64);
        as.w = __shfl(a.w, gb + s, 64);
        const int k0 = s * 4;
        float4 w0 = *(const float4*)&ws[k0 + 0][c0];
        float4 w1 = *(const float4*)&ws[k0 + 1][c0];
        float4 w2 = *(const float4*)&ws[k0 + 2][c0];
        float4 w3 = *(const float4*)&ws[k0 + 3][c0];
        o.x += as.x*w0.x + as.y*w1.x + as.z*w2.x + as.w*w3.x;
        o.y += as.x*w0.y + as.y*w1.y + as.z*w2.y + as.w*w3.y;
        o.z += as.x*w0.z + as.y*w1.z + as.z*w2.z + as.w*w3.z;
        o.w += as.x*w0.w + as.y*w1.w + as.z*w2.w + as.w*w3.w;
    }
    ushort4 st;
    st.x = f2bf(o.x * di); st.y = f2bf(o.y * di);
    st.z = f2bf(o.z * di); st.w = f2bf(o.w * di);
    *(ushort4*)&OUT[(size_t)node * 32 + c0] = st;
}

// agg + bias + relu + dinv scale: OUT(bf16) = dinv.*relu(dinv*agg(HS)+b)
__global__ __launch_bounds__(256) void k_aggscale(const unsigned short* __restrict__ HS,
                                                  const int* __restrict__ row_ptr,
                                                  const int* __restrict__ col,
                                                  const float* __restrict__ dinv,
                                                  const float* __restrict__ bin,
                                                  unsigned short* __restrict__ OUT, int n) {
    const int t    = threadIdx.x;
    const int node = blockIdx.x * 32 + t / 8;
    const int c0   = (t % 8) * 4;
    if (node >= n) return;
    const int s0 = row_ptr[node], s1 = row_ptr[node + 1];
    float4 acc = agg_gather_bf16(HS, col, s0, s1, node, c0);
    const float di = dinv[node];
    float4 b4 = *(const float4*)&bin[c0];
    ushort4 o;
    o.x = f2bf(di * fmaxf(di * acc.x + b4.x, 0.f));
    o.y = f2bf(di * fmaxf(di * acc.y + b4.y, 0.f));
    o.z = f2bf(di * fmaxf(di * acc.z + b4.z, 0.f));
    o.w = f2bf(di * fmaxf(di * acc.w + b4.w, 0.f));
    *(ushort4*)&OUT[(size_t)node * 32 + c0] = o;
}

// final: g = dinv*(agg ys2); h3 = g @ W3 + b3 [32->64]; out = log_softmax(h3)
__global__ __launch_bounds__(256) void k_fuseC(const unsigned short* __restrict__ YS,
                                               const int* __restrict__ row_ptr,
                                               const int* __restrict__ col,
                                               const float* __restrict__ dinv,
                                               const float* __restrict__ b3,
                                               const float* __restrict__ W,
                                               float* __restrict__ OUT, int n) {
    __shared__ float ws[32][64];
    {
        int i = threadIdx.x;                  // 512 float4s = 32x64 -> 2 each
        int r0w = i / 16, cw = (i % 16) * 4;
        *(float4*)&ws[r0w][cw]      = *(const float4*)&W[r0w * 64 + cw];
        *(float4*)&ws[r0w + 16][cw] = *(const float4*)&W[(r0w + 16) * 64 + cw];
    }
    __syncthreads();
    const int t    = threadIdx.x;
    const int node = blockIdx.x * 32 + t / 8;
    const int c0   = (t % 8) * 4;
    if (node >= n) return;
    const int s0 = row_ptr[node], s1 = row_ptr[node + 1];
    float4 acc = agg_gather_bf16(YS, col, s0, s1, node, c0);
    const float di = dinv[node];
    float4 g;
    g.x = di * acc.x; g.y = di * acc.y; g.z = di * acc.z; g.w = di * acc.w;
    float4 oL = {0,0,0,0}, oH = {0,0,0,0};
    const int gb = (t & 63) & ~7;
    #pragma unroll
    for (int s = 0; s < 8; s++) {
        float4 gs;
        gs.x = __shfl(g.x, gb + s, 64);
        gs.y = __shfl(g.y, gb + s, 64);
        gs.z = __shfl(g.z, gb + s, 64);
        gs.w = __shfl(g.w, gb + s, 64);
        const int k0 = s * 4;
        #pragma unroll
        for (int q = 0; q < 4; q++) {
            float gv = (q == 0) ? gs.x : (q == 1) ? gs.y : (q == 2) ? gs.z : gs.w;
            float4 wL = *(const float4*)&ws[k0 + q][c0];
            float4 wH = *(const float4*)&ws[k0 + q][32 + c0];
            oL.x += gv * wL.x; oL.y += gv * wL.y; oL.z += gv * wL.z; oL.w += gv * wL.w;
            oH.x += gv * wH.x; oH.y += gv * wH.y; oH.z += gv * wH.z; oH.w += gv * wH.w;
        }
    }
    float4 bL = *(const float4*)&b3[c0];
    float4 bH = *(const float4*)&b3[32 + c0];
    oL.x += bL.x; oL.y += bL.y; oL.z += bL.z; oL.w += bL.w;
    oH.x += bH.x; oH.y += bH.y; oH.z += bH.z; oH.w += bH.w;
    float m = fmaxf(fmaxf(fmaxf(oL.x, oL.y), fmaxf(oL.z, oL.w)),
                    fmaxf(fmaxf(oH.x, oH.y), fmaxf(oH.z, oH.w)));
    #pragma unroll
    for (int off = 1; off < 8; off <<= 1) m = fmaxf(m, __shfl_xor(m, off, 64));
    float sum = expf(oL.x - m) + expf(oL.y - m) + expf(oL.z - m) + expf(oL.w - m)
              + expf(oH.x - m) + expf(oH.y - m) + expf(oH.z - m) + expf(oH.w - m);
    #pragma unroll
    for (int off = 1; off < 8; off <<= 1) sum += __shfl_xor(sum, off, 64);
    float lse = m + logf(sum);
    float4 rL, rH;
    rL.x = oL.x - lse; rL.y = oL.y - lse; rL.z = oL.z - lse; rL.w = oL.w - lse;
    rH.x = oH.x - lse; rH.y = oH.y - lse; rH.z = oH.z - lse; rH.w = oH.w - lse;
    *(float4*)&OUT[(size_t)node * 64 + c0]      = rL;
    *(float4*)&OUT[(size_t)node * 64 + 32 + c0] = rH;
}

// ------------------------------------------------------------------
extern "C" void kernel_launch(void* const* d_in, const int* in_sizes, int n_in,
                              void* d_out, int out_size, void* d_ws, size_t ws_size,
                              hipStream_t stream) {
    const float* x  = (const float*)d_in[0];
    const int*   ei = (const int*)d_in[1];
    const float* W1 = (const float*)d_in[2];
    const float* b1 = (const float*)d_in[3];
    const float* W2 = (const float*)d_in[4];
    const float* b2 = (const float*)d_in[5];
    const float* W3 = (const float*)d_in[6];
    const float* b3 = (const float*)d_in[7];
    float* out = (float*)d_out;

    const int E = in_sizes[1] / 2;
    const int n = NN;
    const int* src = ei;
    const int* dst = ei + E;

    char* p = (char*)d_ws;
    auto alloc = [&](size_t bytes) -> void* {
        void* r = p;
        p += (bytes + 63) & ~(size_t)63;
        return r;
    };
    int*            bcnt    = (int*)alloc((size_t)NBUCK * 4);
    int*            bbase   = (int*)alloc((size_t)(NBUCK + 1) * 4);
    int*            bfill   = (int*)alloc((size_t)NBUCK * 4);
    unsigned*       part    = (unsigned*)alloc((size_t)E * 4);
    int*            row_ptr = (int*)alloc((size_t)(n + 1) * 4);
    int*            col     = (int*)alloc((size_t)E * 4);
    float*          dinv    = (float*)alloc((size_t)n * 4);
    unsigned short* hs1     = (unsigned short*)alloc((size_t)n * 32 * 2);  // reused as ys2
    unsigned short* hs2     = (unsigned short*)alloc((size_t)n * 32 * 2);

    const int NBLK_A = 256;
    const int chunk  = CDIV(E, NBLK_A);

    k_zero<<<1, 512, 0, stream>>>(bcnt, NBUCK);
    k_bcount<<<NBLK_A, 256, 0, stream>>>(dst, bcnt, E, chunk);
    k_bscan<<<1, 512, 0, stream>>>(bcnt, bbase, bfill, E);
    k_bpart<<<NBLK_A, 256, 0, stream>>>(src, dst, bfill, part, E, chunk);
    k_bbuild<<<NBUCK, 256, 0, stream>>>(part, bbase, row_ptr, dinv, col, n, E);

    // L1 GEMM: hs1 = bf16(dinv.*(x @ W1))
    k_gemm1<<<CDIV(n, 64), 256, 0, stream>>>(x, W1, dinv, hs1, n);
    // L1 agg + relu + L2 GEMM: hs2 = bf16(dinv.*(relu(dinv*agg(hs1)+b1) @ W2))
    k_fuse32<<<CDIV(n, 32), 256, 0, stream>>>(hs1, row_ptr, col, dinv, b1, W2, hs2, n);
    // L2 agg + relu + scale: ys2 = bf16(dinv.*relu(dinv*agg(hs2)+b2))  (reuse hs1)
    k_aggscale<<<CDIV(n, 32), 256, 0, stream>>>(hs2, row_ptr, col, dinv, b2, hs1, n);
    // L3 (commuted): out = lsm( (dinv*agg(ys2)) @ W3 + b3 )
    k_fuseC<<<CDIV(n, 32), 256, 0, stream>>>(hs1, row_ptr, col, dinv, b3, W3, out, n);
}